// Round 1
// 1891.933 us; speedup vs baseline: 1.1629x; 1.1629x over previous
//
#include <hip/hip_runtime.h>
#include <hip/hip_bf16.h>
#include <stdint.h>

// Problem constants (SparseMoE: B=4, T=4096, C=1024, E=8, H=4C, topk=2)
#define NC 1024
#define NE 8
#define NH 4096
#define NN 16384   // B*T tokens

typedef __bf16 bf16x8_t __attribute__((ext_vector_type(8)));
typedef float f32x4_t __attribute__((ext_vector_type(4)));

// Convert 8 fp32 -> 8 bf16, write 16B to LDS/global.
__device__ __forceinline__ void cvt8(const float4 a, const float4 b, __bf16* dst) {
  bf16x8_t r;
  r[0] = (__bf16)a.x; r[1] = (__bf16)a.y; r[2] = (__bf16)a.z; r[3] = (__bf16)a.w;
  r[4] = (__bf16)b.x; r[5] = (__bf16)b.y; r[6] = (__bf16)b.z; r[7] = (__bf16)b.w;
  *(bf16x8_t*)dst = r;
}

// ---------------- routing phase A (fp32 exact, double accum): noisy top-2 + probs per token.
// NO atomics — per-token plain stores only. Math is byte-identical to the verified version.
__global__ __launch_bounds__(256) void routing_kernel(
    const float* __restrict__ x, const float* __restrict__ eps,
    const float* __restrict__ rw, const float* __restrict__ rb,
    const float* __restrict__ nw, const float* __restrict__ nb,
    int* __restrict__ eidx, float2* __restrict__ pp2) {
  const int lane = threadIdx.x & 63;
  const int n = blockIdx.x * 4 + (threadIdx.x >> 6);  // one wave per token
  if (n >= NN) return;
  double acc[16];
#pragma unroll
  for (int i = 0; i < 16; ++i) acc[i] = 0.0;
  const float* xr = x + (size_t)n * NC;
  for (int c0 = 0; c0 < NC; c0 += 64) {
    const int c = c0 + lane;
    const float xv = xr[c];
    const float4 r0 = *(const float4*)(rw + (size_t)c * NE);
    const float4 r1 = *(const float4*)(rw + (size_t)c * NE + 4);
    const float4 n0 = *(const float4*)(nw + (size_t)c * NE);
    const float4 n1 = *(const float4*)(nw + (size_t)c * NE + 4);
    acc[0] += (double)xv * r0.x;  acc[1] += (double)xv * r0.y;
    acc[2] += (double)xv * r0.z;  acc[3] += (double)xv * r0.w;
    acc[4] += (double)xv * r1.x;  acc[5] += (double)xv * r1.y;
    acc[6] += (double)xv * r1.z;  acc[7] += (double)xv * r1.w;
    acc[8] += (double)xv * n0.x;  acc[9] += (double)xv * n0.y;
    acc[10] += (double)xv * n0.z; acc[11] += (double)xv * n0.w;
    acc[12] += (double)xv * n1.x; acc[13] += (double)xv * n1.y;
    acc[14] += (double)xv * n1.z; acc[15] += (double)xv * n1.w;
  }
#pragma unroll
  for (int off = 32; off > 0; off >>= 1) {
#pragma unroll
    for (int i = 0; i < 16; ++i) acc[i] += __shfl_xor(acc[i], off, 64);
  }
  if (lane == 0) {
    double noisy[NE];
#pragma unroll
    for (int e = 0; e < NE; ++e) {
      const double lg = acc[e] + (double)rb[e];
      const double z = acc[8 + e] + (double)nb[e];
      const double sp = log1p(exp(-fabs(z))) + fmax(z, 0.0);  // stable softplus
      noisy[e] = lg + (double)eps[(size_t)n * NE + e] * sp;
    }
    int i1 = -1, i2 = -1;
    double v1 = -1e300, v2 = -1e300;
#pragma unroll
    for (int e = 0; e < NE; ++e) {  // strict > keeps earlier index on ties (lax.top_k)
      const double v = noisy[e];
      if (v > v1) { v2 = v1; i2 = i1; v1 = v; i1 = e; }
      else if (v > v2) { v2 = v; i2 = e; }
    }
    if (i1 < 0) i1 = 0;                       // hardening vs pathological inputs
    if (i2 < 0 || i2 == i1) i2 = (i1 + 1) & 7;
    const double d = exp(v2 - v1);
    const float p1 = (float)(1.0 / (1.0 + d));
    const float p2 = (float)(d / (1.0 + d));
    eidx[n] = i1 | (i2 << 8);
    pp2[n] = float2{p1, p2};
  }
}

// ---------------- routing phase B: build per-expert token lists.
// LDS histogram per block (256 tokens), ONE global atomicAdd per expert per block.
// Global atomics: 64 blocks x 8 = 512 total (vs 32768 per-wave before).
__global__ __launch_bounds__(256) void build_lists(
    const int* __restrict__ eidx, const float2* __restrict__ pp2,
    int* __restrict__ counts, int* __restrict__ perm, float* __restrict__ pprob) {
  __shared__ int hist[NE];
  __shared__ int base[NE];
  const int t = threadIdx.x;
  if (t < NE) hist[t] = 0;
  __syncthreads();
  const int n = blockIdx.x * 256 + t;
  const int packed = eidx[n];
  const int e1 = packed & 255;
  const int e2 = (packed >> 8) & 255;
  const float2 p = pp2[n];
  const int l1 = atomicAdd(&hist[e1], 1);   // LDS atomic: within-block rank
  const int l2 = atomicAdd(&hist[e2], 1);
  __syncthreads();
  if (t < NE) base[t] = atomicAdd(&counts[t], hist[t]);
  __syncthreads();
  const int o1 = base[e1] + l1;
  const int o2 = base[e2] + l2;
  perm[e1 * NN + o1] = n; pprob[e1 * NN + o1] = p.x;
  perm[e2 * NN + o2] = n; pprob[e2 * NN + o2] = p.y;
}

// ---------------- transpose + fp32->bf16: src fp32 [R][Cc] -> dst bf16 [Cc][R] ----------------
__global__ __launch_bounds__(256) void transpose_cvt(
    const float* __restrict__ src, __bf16* __restrict__ dst, int R, int Cc) {
  __shared__ __align__(16) __bf16 tile[64][72];  // +8 pad
  const int r0 = blockIdx.y * 64, c0 = blockIdx.x * 64;
  const int t = threadIdx.x;
  const int tr = t >> 3;            // 0..31
  const int tc = (t & 7) * 8;       // 0..56
#pragma unroll
  for (int h = 0; h < 2; ++h) {
    const int r = tr + h * 32;
    const float* sp = src + (size_t)(r0 + r) * Cc + (c0 + tc);
    const float4 a = *(const float4*)sp;
    const float4 b = *(const float4*)(sp + 4);
    cvt8(a, b, &tile[r][tc]);
  }
  __syncthreads();
#pragma unroll
  for (int h = 0; h < 2; ++h) {
    const int c = tr + h * 32;
    __bf16 tmp[8] __attribute__((aligned(16)));
#pragma unroll
    for (int j = 0; j < 8; ++j) tmp[j] = tile[tc + j][c];
    __bf16* dp = dst + (size_t)(c0 + c) * R + (r0 + tc);
    *(uint4*)dp = *(const uint4*)tmp;
  }
}

// ---------------- GEMM1: h = relu(gather(x) @ w1e + b1), bf16 MFMA ----------------
// FASTB: bsrc = bf16 [NH][NC] pre-transposed (k-contiguous rows).
// !FASTB: bsrc = fp32 [NC][NH] as given (n-contiguous rows), inline cvt.
template<bool FASTB>
__global__ __launch_bounds__(256) void moe_gemm1(
    const float* __restrict__ x, const void* __restrict__ bsrc,
    const float* __restrict__ bias, __bf16* __restrict__ hbuf,
    const int* __restrict__ counts_e, const int* __restrict__ perm_e, int chunk_start) {
  int cnt = *counts_e; if (cnt > NN) cnt = NN; if (cnt < 0) cnt = 0;
  const int lr0 = blockIdx.y * 128;
  const int row0 = chunk_start + lr0;
  if (row0 >= cnt) return;
  const int t = threadIdx.x;

  __shared__ __align__(16) __bf16 As[128 * 32];  // [m][k]
  __shared__ __align__(16) __bf16 Bs[128 * 32];  // FASTB: [n][k]; else [k][n]

  const int ar1 = row0 + (t >> 2), ar2 = ar1 + 64;
  const int tokA = (ar1 < cnt) ? perm_e[ar1] : 0;
  const int tokB = (ar2 < cnt) ? perm_e[ar2] : 0;
  const int kg = (t & 3) * 8;
  const float* pA1 = x + (size_t)tokA * NC + kg;
  const float* pA2 = x + (size_t)tokB * NC + kg;
  const int n0 = blockIdx.x * 128;

  const __bf16* pB1 = nullptr; const __bf16* pB2 = nullptr;  // FASTB
  const float* pBw = nullptr;                                 // !FASTB
  const int kk = t >> 3, cc = (t & 7) * 16;
  if (FASTB) {
    const __bf16* bt = (const __bf16*)bsrc;
    const int nrow = n0 + (t >> 2);
    pB1 = bt + (size_t)nrow * NC + kg;
    pB2 = bt + (size_t)(nrow + 64) * NC + kg;
  } else {
    pBw = (const float*)bsrc + (size_t)kk * NH + n0 + cc;
  }

  f32x4_t acc[4][4];
#pragma unroll
  for (int i = 0; i < 4; ++i)
#pragma unroll
    for (int j = 0; j < 4; ++j)
#pragma unroll
      for (int k = 0; k < 4; ++k) acc[i][j][k] = 0.f;

  const int lane = t & 63, wid = t >> 6;
  const int wm = (wid >> 1) * 64, wn = (wid & 1) * 64;
  const int col16 = lane & 15, quad = lane >> 4;
  const int a_off = (wm + col16) * 32 + quad * 8;
  const int b_off = (wn + col16) * 32 + quad * 8;

  for (int k0 = 0; k0 < NC; k0 += 32) {
    const float4 a1a = *(const float4*)(pA1 + k0);
    const float4 a1b = *(const float4*)(pA1 + k0 + 4);
    const float4 a2a = *(const float4*)(pA2 + k0);
    const float4 a2b = *(const float4*)(pA2 + k0 + 4);
    uint4 vb1, vb2; float4 w0, w1, w2, w3;
    if (FASTB) {
      vb1 = *(const uint4*)(pB1 + k0);
      vb2 = *(const uint4*)(pB2 + k0);
    } else {
      const float* pw = pBw + (size_t)k0 * NH;
      w0 = *(const float4*)pw; w1 = *(const float4*)(pw + 4);
      w2 = *(const float4*)(pw + 8); w3 = *(const float4*)(pw + 12);
    }
    __syncthreads();
    cvt8(a1a, a1b, As + t * 8);
    cvt8(a2a, a2b, As + 2048 + t * 8);
    if (FASTB) {
      *(uint4*)(Bs + t * 8) = vb1;
      *(uint4*)(Bs + 2048 + t * 8) = vb2;
    } else {
      cvt8(w0, w1, Bs + kk * 128 + cc);
      cvt8(w2, w3, Bs + kk * 128 + cc + 8);
    }
    __syncthreads();
    bf16x8_t af[4], bfr[4];
#pragma unroll
    for (int mi = 0; mi < 4; ++mi) af[mi] = *(const bf16x8_t*)(As + a_off + mi * 512);
    if (FASTB) {
#pragma unroll
      for (int ni = 0; ni < 4; ++ni) bfr[ni] = *(const bf16x8_t*)(Bs + b_off + ni * 512);
    } else {
#pragma unroll
      for (int ni = 0; ni < 4; ++ni) {
        const int bn = wn + ni * 16 + col16;
#pragma unroll
        for (int j = 0; j < 8; ++j) bfr[ni][j] = Bs[(quad * 8 + j) * 128 + bn];
      }
    }
#pragma unroll
    for (int mi = 0; mi < 4; ++mi)
#pragma unroll
      for (int ni = 0; ni < 4; ++ni)
        acc[mi][ni] = __builtin_amdgcn_mfma_f32_16x16x32_bf16(af[mi], bfr[ni], acc[mi][ni], 0, 0, 0);
  }

  // C/D: col = lane&15, row = quad*4 + reg (m89-verified)
  const int colbase = n0 + wn + col16;
#pragma unroll
  for (int mi = 0; mi < 4; ++mi)
#pragma unroll
    for (int reg = 0; reg < 4; ++reg) {
      const int lr = lr0 + wm + mi * 16 + quad * 4 + reg;
      if (chunk_start + lr < cnt) {
        __bf16* hp = hbuf + (size_t)lr * NH + colbase;
#pragma unroll
        for (int ni = 0; ni < 4; ++ni) {
          const float v = acc[mi][ni][reg] + bias[colbase + ni * 16];
          hp[ni * 16] = (__bf16)fmaxf(v, 0.f);
        }
      }
    }
}

// ---------------- GEMM2: out[tok] += p * (h @ w2e + b2), fp32 out ----------------
// FASTB: bsrc = bf16 [NC][NH] pre-transposed. !FASTB: bsrc = fp32 [NH][NC].
template<bool FASTB>
__global__ __launch_bounds__(256) void moe_gemm2(
    const __bf16* __restrict__ hbuf, const void* __restrict__ bsrc,
    const float* __restrict__ bias, float* __restrict__ out,
    const int* __restrict__ counts_e, const int* __restrict__ perm_e,
    const float* __restrict__ pprob_e, int chunk_start) {
  int cnt = *counts_e; if (cnt > NN) cnt = NN; if (cnt < 0) cnt = 0;
  const int lr0 = blockIdx.y * 128;
  if (chunk_start + lr0 >= cnt) return;
  const int t = threadIdx.x;

  __shared__ __align__(16) __bf16 As[128 * 32];
  __shared__ __align__(16) __bf16 Bs[128 * 32];

  const int lar1 = lr0 + (t >> 2);
  const int kg = (t & 3) * 8;
  const __bf16* pA1 = hbuf + (size_t)lar1 * NH + kg;
  const __bf16* pA2 = pA1 + (size_t)64 * NH;
  const int n0 = blockIdx.x * 128;

  const __bf16* pB1 = nullptr; const __bf16* pB2 = nullptr;
  const float* pBw = nullptr;
  const int kk = t >> 3, cc = (t & 7) * 16;
  if (FASTB) {
    const __bf16* bt = (const __bf16*)bsrc;
    const int nrow = n0 + (t >> 2);
    pB1 = bt + (size_t)nrow * NH + kg;
    pB2 = bt + (size_t)(nrow + 64) * NH + kg;
  } else {
    pBw = (const float*)bsrc + (size_t)kk * NC + n0 + cc;
  }

  f32x4_t acc[4][4];
#pragma unroll
  for (int i = 0; i < 4; ++i)
#pragma unroll
    for (int j = 0; j < 4; ++j)
#pragma unroll
      for (int k = 0; k < 4; ++k) acc[i][j][k] = 0.f;

  const int lane = t & 63, wid = t >> 6;
  const int wm = (wid >> 1) * 64, wn = (wid & 1) * 64;
  const int col16 = lane & 15, quad = lane >> 4;
  const int a_off = (wm + col16) * 32 + quad * 8;
  const int b_off = (wn + col16) * 32 + quad * 8;

  for (int k0 = 0; k0 < NH; k0 += 32) {
    const uint4 va1 = *(const uint4*)(pA1 + k0);
    const uint4 va2 = *(const uint4*)(pA2 + k0);
    uint4 vb1, vb2; float4 w0, w1, w2, w3;
    if (FASTB) {
      vb1 = *(const uint4*)(pB1 + k0);
      vb2 = *(const uint4*)(pB2 + k0);
    } else {
      const float* pw = pBw + (size_t)k0 * NC;
      w0 = *(const float4*)pw; w1 = *(const float4*)(pw + 4);
      w2 = *(const float4*)(pw + 8); w3 = *(const float4*)(pw + 12);
    }
    __syncthreads();
    *(uint4*)(As + t * 8) = va1;
    *(uint4*)(As + 2048 + t * 8) = va2;
    if (FASTB) {
      *(uint4*)(Bs + t * 8) = vb1;
      *(uint4*)(Bs + 2048 + t * 8) = vb2;
    } else {
      cvt8(w0, w1, Bs + kk * 128 + cc);
      cvt8(w2, w3, Bs + kk * 128 + cc + 8);
    }
    __syncthreads();
    bf16x8_t af[4], bfr[4];
#pragma unroll
    for (int mi = 0; mi < 4; ++mi) af[mi] = *(const bf16x8_t*)(As + a_off + mi * 512);
    if (FASTB) {
#pragma unroll
      for (int ni = 0; ni < 4; ++ni) bfr[ni] = *(const bf16x8_t*)(Bs + b_off + ni * 512);
    } else {
#pragma unroll
      for (int ni = 0; ni < 4; ++ni) {
        const int bn = wn + ni * 16 + col16;
#pragma unroll
        for (int j = 0; j < 8; ++j) bfr[ni][j] = Bs[(quad * 8 + j) * 128 + bn];
      }
    }
#pragma unroll
    for (int mi = 0; mi < 4; ++mi)
#pragma unroll
      for (int ni = 0; ni < 4; ++ni)
        acc[mi][ni] = __builtin_amdgcn_mfma_f32_16x16x32_bf16(af[mi], bfr[ni], acc[mi][ni], 0, 0, 0);
  }

  const int colbase = n0 + wn + col16;
#pragma unroll
  for (int mi = 0; mi < 4; ++mi)
#pragma unroll
    for (int reg = 0; reg < 4; ++reg) {
      const int lr = lr0 + wm + mi * 16 + quad * 4 + reg;
      const int r = chunk_start + lr;
      if (r < cnt) {
        const int tok = perm_e[r];
        const float p = pprob_e[r];
        float* op = out + (size_t)tok * NC + colbase;
#pragma unroll
        for (int ni = 0; ni < 4; ++ni) {
          op[ni * 16] += (acc[mi][ni][reg] + bias[colbase + ni * 16]) * p;  // one writer per (tok,col) per launch
        }
      }
    }
}

extern "C" void kernel_launch(void* const* d_in, const int* in_sizes, int n_in,
                              void* d_out, int out_size, void* d_ws, size_t ws_size,
                              hipStream_t stream) {
  (void)in_sizes; (void)n_in;
  const float* x   = (const float*)d_in[0];
  const float* eps = (const float*)d_in[1];
  const float* rw  = (const float*)d_in[2];
  const float* rb  = (const float*)d_in[3];
  const float* nw  = (const float*)d_in[4];
  const float* nb  = (const float*)d_in[5];
  const float* w1  = (const float*)d_in[6];
  const float* b1  = (const float*)d_in[7];
  const float* w2  = (const float*)d_in[8];
  const float* b2  = (const float*)d_in[9];
  float* out = (float*)d_out;

  // ws: counts(256B) | perm [E][N] | pprob [E][N] | eidx [N] | pp2 [N] | {w1t, w2t bf16 if fast} | hbuf bf16
  char* wsb = (char*)d_ws;
  int* counts = (int*)wsb;
  int* perm = (int*)(wsb + 256);
  float* pprob = (float*)(wsb + 256 + (size_t)NE * NN * 4);
  int* eidx = (int*)(wsb + 256 + (size_t)NE * NN * 8);
  float2* pp2 = (float2*)(wsb + 256 + (size_t)NE * NN * 8 + (size_t)NN * 4);
  size_t off = 256 + (size_t)NE * NN * 8 + (size_t)NN * 12;  // ~1.25 MB

  const size_t wtile = (size_t)NC * NH * 2;  // 8 MB per transposed weight
  const bool fast = ws_size >= off + 2 * wtile + (size_t)128 * NH * 2 + (1u << 20);
  __bf16* w1t = nullptr; __bf16* w2t = nullptr;
  if (fast) {
    w1t = (__bf16*)(wsb + off); off += wtile;
    w2t = (__bf16*)(wsb + off); off += wtile;
  }
  __bf16* hbuf = (__bf16*)(wsb + off);
  const size_t remain = (ws_size > off) ? (ws_size - off) : 0;
  long rows_cap = (long)(remain / ((size_t)NH * 2));
  rows_cap = (rows_cap / 128) * 128;
  if (rows_cap > NN) rows_cap = NN;
  if (rows_cap < 128) rows_cap = 128;  // floor; needs ws >= ~2.3 MB

  hipMemsetAsync(counts, 0, 256, stream);
  hipMemsetAsync(d_out, 0, (size_t)out_size * 4, stream);

  routing_kernel<<<NN / 4, 256, 0, stream>>>(x, eps, rw, rb, nw, nb, eidx, pp2);
  build_lists<<<NN / 256, 256, 0, stream>>>(eidx, pp2, counts, perm, pprob);

  const int nchunks = (int)((NN + rows_cap - 1) / rows_cap);
  for (int e = 0; e < NE; ++e) {
    const float* w1e = w1 + (size_t)e * NC * NH;  // [C][H] fp32
    const float* w2e = w2 + (size_t)e * NH * NC;  // [H][C] fp32
    if (fast) {
      transpose_cvt<<<dim3(NH / 64, NC / 64), 256, 0, stream>>>(w1e, w1t, NC, NH);
      transpose_cvt<<<dim3(NC / 64, NH / 64), 256, 0, stream>>>(w2e, w2t, NH, NC);
    }
    for (int ch = 0; ch < nchunks; ++ch) {
      const int cs = ch * (int)rows_cap;
      if (fast) {
        moe_gemm1<true><<<dim3(NH / 128, (unsigned)(rows_cap / 128)), 256, 0, stream>>>(
            x, w1t, b1 + (size_t)e * NH, hbuf, counts + e, perm + (size_t)e * NN, cs);
        moe_gemm2<true><<<dim3(NC / 128, (unsigned)(rows_cap / 128)), 256, 0, stream>>>(
            hbuf, w2t, b2 + (size_t)e * NC, out, counts + e, perm + (size_t)e * NN,
            pprob + (size_t)e * NN, cs);
      } else {
        moe_gemm1<false><<<dim3(NH / 128, (unsigned)(rows_cap / 128)), 256, 0, stream>>>(
            x, w1e, b1 + (size_t)e * NH, hbuf, counts + e, perm + (size_t)e * NN, cs);
        moe_gemm2<false><<<dim3(NC / 128, (unsigned)(rows_cap / 128)), 256, 0, stream>>>(
            hbuf, w2e, b2 + (size_t)e * NC, out, counts + e, perm + (size_t)e * NN,
            pprob + (size_t)e * NN, cs);
      }
    }
  }
}

// Round 3
// 1867.634 us; speedup vs baseline: 1.1780x; 1.0130x over previous
//
#include <hip/hip_runtime.h>
#include <hip/hip_bf16.h>
#include <stdint.h>

// Problem constants (SparseMoE: B=4, T=4096, C=1024, E=8, H=4C, topk=2)
#define NC 1024
#define NE 8
#define NH 4096
#define NN 16384   // B*T tokens

typedef __bf16 bf16x8_t __attribute__((ext_vector_type(8)));
typedef float f32x4_t __attribute__((ext_vector_type(4)));

// Convert 8 fp32 -> 8 bf16, write 16B to LDS/global.
__device__ __forceinline__ void cvt8(const float4 a, const float4 b, __bf16* dst) {
  bf16x8_t r;
  r[0] = (__bf16)a.x; r[1] = (__bf16)a.y; r[2] = (__bf16)a.z; r[3] = (__bf16)a.w;
  r[4] = (__bf16)b.x; r[5] = (__bf16)b.y; r[6] = (__bf16)b.z; r[7] = (__bf16)b.w;
  *(bf16x8_t*)dst = r;
}

// ---------------- routing phase A (fp32 exact, double accum): noisy top-2 + probs per token.
// NO atomics — per-token plain stores only.
__global__ __launch_bounds__(256) void routing_kernel(
    const float* __restrict__ x, const float* __restrict__ eps,
    const float* __restrict__ rw, const float* __restrict__ rb,
    const float* __restrict__ nw, const float* __restrict__ nb,
    int* __restrict__ eidx, float2* __restrict__ pp2) {
  const int lane = threadIdx.x & 63;
  const int n = blockIdx.x * 4 + (threadIdx.x >> 6);  // one wave per token
  if (n >= NN) return;
  double acc[16];
#pragma unroll
  for (int i = 0; i < 16; ++i) acc[i] = 0.0;
  const float* xr = x + (size_t)n * NC;
  for (int c0 = 0; c0 < NC; c0 += 64) {
    const int c = c0 + lane;
    const float xv = xr[c];
    const float4 r0 = *(const float4*)(rw + (size_t)c * NE);
    const float4 r1 = *(const float4*)(rw + (size_t)c * NE + 4);
    const float4 n0 = *(const float4*)(nw + (size_t)c * NE);
    const float4 n1 = *(const float4*)(nw + (size_t)c * NE + 4);
    acc[0] += (double)xv * r0.x;  acc[1] += (double)xv * r0.y;
    acc[2] += (double)xv * r0.z;  acc[3] += (double)xv * r0.w;
    acc[4] += (double)xv * r1.x;  acc[5] += (double)xv * r1.y;
    acc[6] += (double)xv * r1.z;  acc[7] += (double)xv * r1.w;
    acc[8] += (double)xv * n0.x;  acc[9] += (double)xv * n0.y;
    acc[10] += (double)xv * n0.z; acc[11] += (double)xv * n0.w;
    acc[12] += (double)xv * n1.x; acc[13] += (double)xv * n1.y;
    acc[14] += (double)xv * n1.z; acc[15] += (double)xv * n1.w;
  }
#pragma unroll
  for (int off = 32; off > 0; off >>= 1) {
#pragma unroll
    for (int i = 0; i < 16; ++i) acc[i] += __shfl_xor(acc[i], off, 64);
  }
  if (lane == 0) {
    double noisy[NE];
#pragma unroll
    for (int e = 0; e < NE; ++e) {
      const double lg = acc[e] + (double)rb[e];
      const double z = acc[8 + e] + (double)nb[e];
      const double sp = log1p(exp(-fabs(z))) + fmax(z, 0.0);  // stable softplus
      noisy[e] = lg + (double)eps[(size_t)n * NE + e] * sp;
    }
    int i1 = -1, i2 = -1;
    double v1 = -1e300, v2 = -1e300;
#pragma unroll
    for (int e = 0; e < NE; ++e) {  // strict > keeps earlier index on ties (lax.top_k)
      const double v = noisy[e];
      if (v > v1) { v2 = v1; i2 = i1; v1 = v; i1 = e; }
      else if (v > v2) { v2 = v; i2 = e; }
    }
    if (i1 < 0) i1 = 0;                       // hardening vs pathological inputs
    if (i2 < 0 || i2 == i1) i2 = (i1 + 1) & 7;
    const double d = exp(v2 - v1);
    const float p1 = (float)(1.0 / (1.0 + d));
    const float p2 = (float)(d / (1.0 + d));
    eidx[n] = i1 | (i2 << 8);
    pp2[n] = float2{p1, p2};
  }
}

// ---------------- routing phase B: build per-expert token lists.
// LDS histogram per block (256 tokens), ONE global atomicAdd per expert per block.
__global__ __launch_bounds__(256) void build_lists(
    const int* __restrict__ eidx, const float2* __restrict__ pp2,
    int* __restrict__ counts, int* __restrict__ perm, float* __restrict__ pprob) {
  __shared__ int hist[NE];
  __shared__ int base[NE];
  const int t = threadIdx.x;
  if (t < NE) hist[t] = 0;
  __syncthreads();
  const int n = blockIdx.x * 256 + t;
  const int packed = eidx[n];
  const int e1 = packed & 255;
  const int e2 = (packed >> 8) & 255;
  const float2 p = pp2[n];
  const int l1 = atomicAdd(&hist[e1], 1);   // LDS atomic: within-block rank
  const int l2 = atomicAdd(&hist[e2], 1);
  __syncthreads();
  if (t < NE) base[t] = atomicAdd(&counts[t], hist[t]);
  __syncthreads();
  const int o1 = base[e1] + l1;
  const int o2 = base[e2] + l2;
  perm[e1 * NN + o1] = n; pprob[e1 * NN + o1] = p.x;
  perm[e2 * NN + o2] = n; pprob[e2 * NN + o2] = p.y;
}

// ---------------- transpose + fp32->bf16: src fp32 [R][Cc] -> dst bf16 [Cc][R] ----------------
__global__ __launch_bounds__(256) void transpose_cvt(
    const float* __restrict__ src, __bf16* __restrict__ dst, int R, int Cc) {
  __shared__ __align__(16) __bf16 tile[64][72];  // +8 pad
  const int r0 = blockIdx.y * 64, c0 = blockIdx.x * 64;
  const int t = threadIdx.x;
  const int tr = t >> 3;            // 0..31
  const int tc = (t & 7) * 8;       // 0..56
#pragma unroll
  for (int h = 0; h < 2; ++h) {
    const int r = tr + h * 32;
    const float* sp = src + (size_t)(r0 + r) * Cc + (c0 + tc);
    const float4 a = *(const float4*)sp;
    const float4 b = *(const float4*)(sp + 4);
    cvt8(a, b, &tile[r][tc]);
  }
  __syncthreads();
#pragma unroll
  for (int h = 0; h < 2; ++h) {
    const int c = tr + h * 32;
    __bf16 tmp[8] __attribute__((aligned(16)));
#pragma unroll
    for (int j = 0; j < 8; ++j) tmp[j] = tile[tc + j][c];
    __bf16* dp = dst + (size_t)(c0 + c) * R + (r0 + tc);
    *(uint4*)dp = *(const uint4*)tmp;
  }
}

// ---------------- GEMM1: h = relu(gather(x) @ w1e + b1), bf16 MFMA ----------------
// FASTB: bsrc = bf16 [NH][NC] pre-transposed (k-contiguous rows).
// !FASTB: bsrc = fp32 [NC][NH] as given (n-contiguous rows), inline cvt.
template<bool FASTB>
__global__ __launch_bounds__(256) void moe_gemm1(
    const float* __restrict__ x, const void* __restrict__ bsrc,
    const float* __restrict__ bias, __bf16* __restrict__ hbuf,
    const int* __restrict__ counts_e, const int* __restrict__ perm_e, int chunk_start) {
  int cnt = *counts_e; if (cnt > NN) cnt = NN; if (cnt < 0) cnt = 0;
  const int lr0 = blockIdx.y * 128;
  const int row0 = chunk_start + lr0;
  if (row0 >= cnt) return;
  const int t = threadIdx.x;

  __shared__ __align__(16) __bf16 As[128 * 32];  // [m][k]
  __shared__ __align__(16) __bf16 Bs[128 * 32];  // FASTB: [n][k]; else [k][n]

  const int ar1 = row0 + (t >> 2), ar2 = ar1 + 64;
  const int tokA = (ar1 < cnt) ? perm_e[ar1] : 0;
  const int tokB = (ar2 < cnt) ? perm_e[ar2] : 0;
  const int kg = (t & 3) * 8;
  const float* pA1 = x + (size_t)tokA * NC + kg;
  const float* pA2 = x + (size_t)tokB * NC + kg;
  const int n0 = blockIdx.x * 128;

  const __bf16* pB1 = nullptr; const __bf16* pB2 = nullptr;  // FASTB
  const float* pBw = nullptr;                                 // !FASTB
  const int kk = t >> 3, cc = (t & 7) * 16;
  if (FASTB) {
    const __bf16* bt = (const __bf16*)bsrc;
    const int nrow = n0 + (t >> 2);
    pB1 = bt + (size_t)nrow * NC + kg;
    pB2 = bt + (size_t)(nrow + 64) * NC + kg;
  } else {
    pBw = (const float*)bsrc + (size_t)kk * NH + n0 + cc;
  }

  f32x4_t acc[4][4];
#pragma unroll
  for (int i = 0; i < 4; ++i)
#pragma unroll
    for (int j = 0; j < 4; ++j)
#pragma unroll
      for (int k = 0; k < 4; ++k) acc[i][j][k] = 0.f;

  const int lane = t & 63, wid = t >> 6;
  const int wm = (wid >> 1) * 64, wn = (wid & 1) * 64;
  const int col16 = lane & 15, quad = lane >> 4;
  const int a_off = (wm + col16) * 32 + quad * 8;
  const int b_off = (wn + col16) * 32 + quad * 8;

  for (int k0 = 0; k0 < NC; k0 += 32) {
    const float4 a1a = *(const float4*)(pA1 + k0);
    const float4 a1b = *(const float4*)(pA1 + k0 + 4);
    const float4 a2a = *(const float4*)(pA2 + k0);
    const float4 a2b = *(const float4*)(pA2 + k0 + 4);
    uint4 vb1, vb2; float4 w0, w1, w2, w3;
    if (FASTB) {
      vb1 = *(const uint4*)(pB1 + k0);
      vb2 = *(const uint4*)(pB2 + k0);
    } else {
      const float* pw = pBw + (size_t)k0 * NH;
      w0 = *(const float4*)pw; w1 = *(const float4*)(pw + 4);
      w2 = *(const float4*)(pw + 8); w3 = *(const float4*)(pw + 12);
    }
    __syncthreads();
    cvt8(a1a, a1b, As + t * 8);
    cvt8(a2a, a2b, As + 2048 + t * 8);
    if (FASTB) {
      *(uint4*)(Bs + t * 8) = vb1;
      *(uint4*)(Bs + 2048 + t * 8) = vb2;
    } else {
      cvt8(w0, w1, Bs + kk * 128 + cc);
      cvt8(w2, w3, Bs + kk * 128 + cc + 8);
    }
    __syncthreads();
    bf16x8_t af[4], bfr[4];
#pragma unroll
    for (int mi = 0; mi < 4; ++mi) af[mi] = *(const bf16x8_t*)(As + a_off + mi * 512);
    if (FASTB) {
#pragma unroll
      for (int ni = 0; ni < 4; ++ni) bfr[ni] = *(const bf16x8_t*)(Bs + b_off + ni * 512);
    } else {
#pragma unroll
      for (int ni = 0; ni < 4; ++ni) {
        const int bn = wn + ni * 16 + col16;
#pragma unroll
        for (int j = 0; j < 8; ++j) bfr[ni][j] = Bs[(quad * 8 + j) * 128 + bn];
      }
    }
#pragma unroll
    for (int mi = 0; mi < 4; ++mi)
#pragma unroll
      for (int ni = 0; ni < 4; ++ni)
        acc[mi][ni] = __builtin_amdgcn_mfma_f32_16x16x32_bf16(af[mi], bfr[ni], acc[mi][ni], 0, 0, 0);
  }

  // C/D: col = lane&15, row = quad*4 + reg (m89-verified)
  const int colbase = n0 + wn + col16;
#pragma unroll
  for (int mi = 0; mi < 4; ++mi)
#pragma unroll
    for (int reg = 0; reg < 4; ++reg) {
      const int lr = lr0 + wm + mi * 16 + quad * 4 + reg;
      if (chunk_start + lr < cnt) {
        __bf16* hp = hbuf + (size_t)lr * NH + colbase;
#pragma unroll
        for (int ni = 0; ni < 4; ++ni) {
          const float v = acc[mi][ni][reg] + bias[colbase + ni * 16];
          hp[ni * 16] = (__bf16)fmaxf(v, 0.f);
        }
      }
    }
}

// ---------------- GEMM2: out[tok] += p * (h @ w2e + b2), fp32 out ----------------
// 1024-thread block: 4 x 256-thread sub-groups, each runs the 128x128 tile over its own
// contiguous K-quarter (NH/4) with its own 16 KB LDS slice. Grid is only ~256 active
// blocks (N=1024 -> 8 x-tiles), so fat blocks raise occupancy 1 -> 4 waves/SIMD.
// After the K-loop: 3-round vectorized LDS reduction of partials; sub-group 0 writes.
// FASTB: bsrc = bf16 [NC][NH] pre-transposed. !FASTB: bsrc = fp32 [NH][NC].
template<bool FASTB>
__global__ __launch_bounds__(1024) void moe_gemm2(
    const __bf16* __restrict__ hbuf, const void* __restrict__ bsrc,
    const float* __restrict__ bias, float* __restrict__ out,
    const int* __restrict__ counts_e, const int* __restrict__ perm_e,
    const float* __restrict__ pprob_e, int chunk_start) {
  int cnt = *counts_e; if (cnt > NN) cnt = NN; if (cnt < 0) cnt = 0;
  const int lr0 = blockIdx.y * 128;
  if (chunk_start + lr0 >= cnt) return;
  const int t = threadIdx.x;
  const int ksub = t >> 8;        // K-segment 0..3, each covers NH/4 = 1024
  const int tt = t & 255;

  __shared__ __align__(16) __bf16 smem[32768];   // 64 KB: As[4][128*32] | Bs[4][128*32]
  __bf16* As = smem + ksub * 4096;
  __bf16* Bs = smem + 16384 + ksub * 4096;

  const int lar1 = lr0 + (tt >> 2);
  const int kg = (tt & 3) * 8;
  const int kbase = ksub * (NH / 4);
  const __bf16* pA1 = hbuf + (size_t)lar1 * NH + kbase + kg;
  const __bf16* pA2 = pA1 + (size_t)64 * NH;
  const int n0 = blockIdx.x * 128;

  const __bf16* pB1 = nullptr; const __bf16* pB2 = nullptr;
  const float* pBw = nullptr;
  const int kk = tt >> 3, cc = (tt & 7) * 16;
  if (FASTB) {
    const __bf16* bt = (const __bf16*)bsrc;
    const int nrow = n0 + (tt >> 2);
    pB1 = bt + (size_t)nrow * NH + kbase + kg;
    pB2 = bt + (size_t)(nrow + 64) * NH + kbase + kg;
  } else {
    pBw = (const float*)bsrc + (size_t)(kbase + kk) * NC + n0 + cc;
  }

  f32x4_t acc[4][4];
#pragma unroll
  for (int i = 0; i < 4; ++i)
#pragma unroll
    for (int j = 0; j < 4; ++j)
#pragma unroll
      for (int k = 0; k < 4; ++k) acc[i][j][k] = 0.f;

  const int lane = tt & 63, wid = tt >> 6;
  const int wm = (wid >> 1) * 64, wn = (wid & 1) * 64;
  const int col16 = lane & 15, quad = lane >> 4;
  const int a_off = (wm + col16) * 32 + quad * 8;
  const int b_off = (wn + col16) * 32 + quad * 8;

  for (int k0 = 0; k0 < NH / 4; k0 += 32) {
    const uint4 va1 = *(const uint4*)(pA1 + k0);
    const uint4 va2 = *(const uint4*)(pA2 + k0);
    uint4 vb1, vb2; float4 w0, w1, w2, w3;
    if (FASTB) {
      vb1 = *(const uint4*)(pB1 + k0);
      vb2 = *(const uint4*)(pB2 + k0);
    } else {
      const float* pw = pBw + (size_t)k0 * NC;
      w0 = *(const float4*)pw; w1 = *(const float4*)(pw + 4);
      w2 = *(const float4*)(pw + 8); w3 = *(const float4*)(pw + 12);
    }
    __syncthreads();
    *(uint4*)(As + tt * 8) = va1;
    *(uint4*)(As + 2048 + tt * 8) = va2;
    if (FASTB) {
      *(uint4*)(Bs + tt * 8) = vb1;
      *(uint4*)(Bs + 2048 + tt * 8) = vb2;
    } else {
      cvt8(w0, w1, Bs + kk * 128 + cc);
      cvt8(w2, w3, Bs + kk * 128 + cc + 8);
    }
    __syncthreads();
    bf16x8_t af[4], bfr[4];
#pragma unroll
    for (int mi = 0; mi < 4; ++mi) af[mi] = *(const bf16x8_t*)(As + a_off + mi * 512);
    if (FASTB) {
#pragma unroll
      for (int ni = 0; ni < 4; ++ni) bfr[ni] = *(const bf16x8_t*)(Bs + b_off + ni * 512);
    } else {
#pragma unroll
      for (int ni = 0; ni < 4; ++ni) {
        const int bn = wn + ni * 16 + col16;
#pragma unroll
        for (int j = 0; j < 8; ++j) bfr[ni][j] = Bs[(quad * 8 + j) * 128 + bn];
      }
    }
#pragma unroll
    for (int mi = 0; mi < 4; ++mi)
#pragma unroll
      for (int ni = 0; ni < 4; ++ni)
        acc[mi][ni] = __builtin_amdgcn_mfma_f32_16x16x32_bf16(af[mi], bfr[ni], acc[mi][ni], 0, 0, 0);
  }

  // Cross-segment K-reduction in LDS. red[j*256 + tt] layout: adjacent threads hit
  // adjacent 16B slots -> conflict-free ds_{write,read}_b128. 3 rounds x 64 KB.
  __syncthreads();
  f32x4_t* red = (f32x4_t*)smem;   // 4096 entries = 64 KB
  for (int r = 1; r < 4; ++r) {
    if (ksub == r) {
#pragma unroll
      for (int mi = 0; mi < 4; ++mi)
#pragma unroll
        for (int ni = 0; ni < 4; ++ni)
          red[(mi * 4 + ni) * 256 + tt] = acc[mi][ni];
    }
    __syncthreads();
    if (ksub == 0) {
#pragma unroll
      for (int mi = 0; mi < 4; ++mi)
#pragma unroll
        for (int ni = 0; ni < 4; ++ni)
          acc[mi][ni] += red[(mi * 4 + ni) * 256 + tt];
    }
    __syncthreads();
  }
  if (ksub != 0) return;

  const int colbase = n0 + wn + col16;
#pragma unroll
  for (int mi = 0; mi < 4; ++mi)
#pragma unroll
    for (int reg = 0; reg < 4; ++reg) {
      const int lr = lr0 + wm + mi * 16 + quad * 4 + reg;
      const int r = chunk_start + lr;
      if (r < cnt) {
        const int tok = perm_e[r];
        const float p = pprob_e[r];
        float* op = out + (size_t)tok * NC + colbase;
#pragma unroll
        for (int ni = 0; ni < 4; ++ni) {
          op[ni * 16] += (acc[mi][ni][reg] + bias[colbase + ni * 16]) * p;  // one writer per (tok,col) per launch
        }
      }
    }
}

extern "C" void kernel_launch(void* const* d_in, const int* in_sizes, int n_in,
                              void* d_out, int out_size, void* d_ws, size_t ws_size,
                              hipStream_t stream) {
  (void)in_sizes; (void)n_in;
  const float* x   = (const float*)d_in[0];
  const float* eps = (const float*)d_in[1];
  const float* rw  = (const float*)d_in[2];
  const float* rb  = (const float*)d_in[3];
  const float* nw  = (const float*)d_in[4];
  const float* nb  = (const float*)d_in[5];
  const float* w1  = (const float*)d_in[6];
  const float* b1  = (const float*)d_in[7];
  const float* w2  = (const float*)d_in[8];
  const float* b2  = (const float*)d_in[9];
  float* out = (float*)d_out;

  // ws: counts(256B) | perm [E][N] | pprob [E][N] | eidx [N] | pp2 [N] | {w1t, w2t bf16 if fast} | hbuf bf16
  char* wsb = (char*)d_ws;
  int* counts = (int*)wsb;
  int* perm = (int*)(wsb + 256);
  float* pprob = (float*)(wsb + 256 + (size_t)NE * NN * 4);
  int* eidx = (int*)(wsb + 256 + (size_t)NE * NN * 8);
  float2* pp2 = (float2*)(wsb + 256 + (size_t)NE * NN * 8 + (size_t)NN * 4);
  size_t off = 256 + (size_t)NE * NN * 8 + (size_t)NN * 12;  // ~1.25 MB

  const size_t wtile = (size_t)NC * NH * 2;  // 8 MB per transposed weight
  const bool fast = ws_size >= off + 2 * wtile + (size_t)128 * NH * 2 + (1u << 20);
  __bf16* w1t = nullptr; __bf16* w2t = nullptr;
  if (fast) {
    w1t = (__bf16*)(wsb + off); off += wtile;
    w2t = (__bf16*)(wsb + off); off += wtile;
  }
  __bf16* hbuf = (__bf16*)(wsb + off);
  const size_t remain = (ws_size > off) ? (ws_size - off) : 0;
  long rows_cap = (long)(remain / ((size_t)NH * 2));
  rows_cap = (rows_cap / 128) * 128;
  if (rows_cap > NN) rows_cap = NN;
  if (rows_cap < 128) rows_cap = 128;  // floor; needs ws >= ~2.3 MB

  hipMemsetAsync(counts, 0, 256, stream);
  hipMemsetAsync(d_out, 0, (size_t)out_size * 4, stream);

  routing_kernel<<<NN / 4, 256, 0, stream>>>(x, eps, rw, rb, nw, nb, eidx, pp2);
  build_lists<<<NN / 256, 256, 0, stream>>>(eidx, pp2, counts, perm, pprob);

  const int nchunks = (int)((NN + rows_cap - 1) / rows_cap);
  for (int e = 0; e < NE; ++e) {
    const float* w1e = w1 + (size_t)e * NC * NH;  // [C][H] fp32
    const float* w2e = w2 + (size_t)e * NH * NC;  // [H][C] fp32
    if (fast) {
      transpose_cvt<<<dim3(NH / 64, NC / 64), 256, 0, stream>>>(w1e, w1t, NC, NH);
      transpose_cvt<<<dim3(NC / 64, NH / 64), 256, 0, stream>>>(w2e, w2t, NH, NC);
    }
    for (int ch = 0; ch < nchunks; ++ch) {
      const int cs = ch * (int)rows_cap;
      if (fast) {
        moe_gemm1<true><<<dim3(NH / 128, (unsigned)(rows_cap / 128)), 256, 0, stream>>>(
            x, w1t, b1 + (size_t)e * NH, hbuf, counts + e, perm + (size_t)e * NN, cs);
        moe_gemm2<true><<<dim3(NC / 128, (unsigned)(rows_cap / 128)), 1024, 0, stream>>>(
            hbuf, w2t, b2 + (size_t)e * NC, out, counts + e, perm + (size_t)e * NN,
            pprob + (size_t)e * NN, cs);
      } else {
        moe_gemm1<false><<<dim3(NH / 128, (unsigned)(rows_cap / 128)), 256, 0, stream>>>(
            x, w1e, b1 + (size_t)e * NH, hbuf, counts + e, perm + (size_t)e * NN, cs);
        moe_gemm2<false><<<dim3(NC / 128, (unsigned)(rows_cap / 128)), 1024, 0, stream>>>(
            hbuf, w2e, b2 + (size_t)e * NC, out, counts + e, perm + (size_t)e * NN,
            pprob + (size_t)e * NN, cs);
      }
    }
  }
}

// Round 4
// 1717.243 us; speedup vs baseline: 1.2812x; 1.0876x over previous
//
#include <hip/hip_runtime.h>
#include <hip/hip_bf16.h>
#include <stdint.h>

// Problem constants (SparseMoE: B=4, T=4096, C=1024, E=8, H=4C, topk=2)
#define NC 1024
#define NE 8
#define NH 4096
#define NN 16384   // B*T tokens

typedef __bf16 bf16x8_t __attribute__((ext_vector_type(8)));
typedef float f32x4_t __attribute__((ext_vector_type(4)));

// Convert 8 fp32 -> 8 bf16, write 16B to LDS/global.
__device__ __forceinline__ void cvt8(const float4 a, const float4 b, __bf16* dst) {
  bf16x8_t r;
  r[0] = (__bf16)a.x; r[1] = (__bf16)a.y; r[2] = (__bf16)a.z; r[3] = (__bf16)a.w;
  r[4] = (__bf16)b.x; r[5] = (__bf16)b.y; r[6] = (__bf16)b.z; r[7] = (__bf16)b.w;
  *(bf16x8_t*)dst = r;
}

// ---------------- routing phase A (fp32 exact, double accum): noisy top-2 + probs per token.
__global__ __launch_bounds__(256) void routing_kernel(
    const float* __restrict__ x, const float* __restrict__ eps,
    const float* __restrict__ rw, const float* __restrict__ rb,
    const float* __restrict__ nw, const float* __restrict__ nb,
    int* __restrict__ eidx, float2* __restrict__ pp2) {
  const int lane = threadIdx.x & 63;
  const int n = blockIdx.x * 4 + (threadIdx.x >> 6);  // one wave per token
  if (n >= NN) return;
  double acc[16];
#pragma unroll
  for (int i = 0; i < 16; ++i) acc[i] = 0.0;
  const float* xr = x + (size_t)n * NC;
  for (int c0 = 0; c0 < NC; c0 += 64) {
    const int c = c0 + lane;
    const float xv = xr[c];
    const float4 r0 = *(const float4*)(rw + (size_t)c * NE);
    const float4 r1 = *(const float4*)(rw + (size_t)c * NE + 4);
    const float4 n0 = *(const float4*)(nw + (size_t)c * NE);
    const float4 n1 = *(const float4*)(nw + (size_t)c * NE + 4);
    acc[0] += (double)xv * r0.x;  acc[1] += (double)xv * r0.y;
    acc[2] += (double)xv * r0.z;  acc[3] += (double)xv * r0.w;
    acc[4] += (double)xv * r1.x;  acc[5] += (double)xv * r1.y;
    acc[6] += (double)xv * r1.z;  acc[7] += (double)xv * r1.w;
    acc[8] += (double)xv * n0.x;  acc[9] += (double)xv * n0.y;
    acc[10] += (double)xv * n0.z; acc[11] += (double)xv * n0.w;
    acc[12] += (double)xv * n1.x; acc[13] += (double)xv * n1.y;
    acc[14] += (double)xv * n1.z; acc[15] += (double)xv * n1.w;
  }
#pragma unroll
  for (int off = 32; off > 0; off >>= 1) {
#pragma unroll
    for (int i = 0; i < 16; ++i) acc[i] += __shfl_xor(acc[i], off, 64);
  }
  if (lane == 0) {
    double noisy[NE];
#pragma unroll
    for (int e = 0; e < NE; ++e) {
      const double lg = acc[e] + (double)rb[e];
      const double z = acc[8 + e] + (double)nb[e];
      const double sp = log1p(exp(-fabs(z))) + fmax(z, 0.0);  // stable softplus
      noisy[e] = lg + (double)eps[(size_t)n * NE + e] * sp;
    }
    int i1 = -1, i2 = -1;
    double v1 = -1e300, v2 = -1e300;
#pragma unroll
    for (int e = 0; e < NE; ++e) {  // strict > keeps earlier index on ties (lax.top_k)
      const double v = noisy[e];
      if (v > v1) { v2 = v1; i2 = i1; v1 = v; i1 = e; }
      else if (v > v2) { v2 = v; i2 = e; }
    }
    if (i1 < 0) i1 = 0;                       // hardening vs pathological inputs
    if (i2 < 0 || i2 == i1) i2 = (i1 + 1) & 7;
    const double d = exp(v2 - v1);
    const float p1 = (float)(1.0 / (1.0 + d));
    const float p2 = (float)(d / (1.0 + d));
    eidx[n] = i1 | (i2 << 8);
    pp2[n] = float2{p1, p2};
  }
}

// ---------------- routing phase B: per-expert token lists, block-aggregated atomics.
__global__ __launch_bounds__(256) void build_lists(
    const int* __restrict__ eidx, const float2* __restrict__ pp2,
    int* __restrict__ counts, int* __restrict__ perm, float* __restrict__ pprob) {
  __shared__ int hist[NE];
  __shared__ int base[NE];
  const int t = threadIdx.x;
  if (t < NE) hist[t] = 0;
  __syncthreads();
  const int n = blockIdx.x * 256 + t;
  const int packed = eidx[n];
  const int e1 = packed & 255;
  const int e2 = (packed >> 8) & 255;
  const float2 p = pp2[n];
  const int l1 = atomicAdd(&hist[e1], 1);   // LDS atomic: within-block rank
  const int l2 = atomicAdd(&hist[e2], 1);
  __syncthreads();
  if (t < NE) base[t] = atomicAdd(&counts[t], hist[t]);
  __syncthreads();
  const int o1 = base[e1] + l1;
  const int o2 = base[e2] + l2;
  perm[e1 * NN + o1] = n; pprob[e1 * NN + o1] = p.x;
  perm[e2 * NN + o2] = n; pprob[e2 * NN + o2] = p.y;
}

// ---------------- transpose + fp32->bf16: src fp32 [R][Cc] -> dst bf16 [Cc][R] ----------------
__global__ __launch_bounds__(256) void transpose_cvt(
    const float* __restrict__ src, __bf16* __restrict__ dst, int R, int Cc) {
  __shared__ __align__(16) __bf16 tile[64][72];  // +8 pad
  const int r0 = blockIdx.y * 64, c0 = blockIdx.x * 64;
  const int t = threadIdx.x;
  const int tr = t >> 3;            // 0..31
  const int tc = (t & 7) * 8;       // 0..56
#pragma unroll
  for (int h = 0; h < 2; ++h) {
    const int r = tr + h * 32;
    const float* sp = src + (size_t)(r0 + r) * Cc + (c0 + tc);
    const float4 a = *(const float4*)sp;
    const float4 b = *(const float4*)(sp + 4);
    cvt8(a, b, &tile[r][tc]);
  }
  __syncthreads();
#pragma unroll
  for (int h = 0; h < 2; ++h) {
    const int c = tr + h * 32;
    __bf16 tmp[8] __attribute__((aligned(16)));
#pragma unroll
    for (int j = 0; j < 8; ++j) tmp[j] = tile[tc + j][c];
    __bf16* dp = dst + (size_t)(c0 + c) * R + (r0 + tc);
    *(uint4*)dp = *(const uint4*)tmp;
  }
}

// LDS tile geometry (shared by both GEMMs, FASTB path):
//   As/Bs: 128 rows x 32 k bf16, row = 64 B = 4 chunks of 16 B.
//   T2 XOR-swizzle: chunk kc of row r stored at kc ^ ((r>>1)&3).
//   -> fragment ds_read_b128: quad lanes spread over all 8 bank-groups, 2-way (free).
//   Double-buffered (x2) + reg-prefetch: single barrier per K-iter.

// ---------------- GEMM1: h = relu(gather(x) @ w1e + b1), bf16 MFMA ----------------
template<bool FASTB>
__global__ __launch_bounds__(256) void moe_gemm1(
    const float* __restrict__ x, const void* __restrict__ bsrc,
    const float* __restrict__ bias, __bf16* __restrict__ hbuf,
    const int* __restrict__ counts_e, const int* __restrict__ perm_e, int chunk_start) {
  int cnt = *counts_e; if (cnt > NN) cnt = NN; if (cnt < 0) cnt = 0;
  const int lr0 = blockIdx.y * 128;
  const int row0 = chunk_start + lr0;
  if (row0 >= cnt) return;
  const int t = threadIdx.x;

  __shared__ __align__(16) __bf16 As[2 * 128 * 32];
  __shared__ __align__(16) __bf16 Bs[2 * 128 * 32];

  const int ar1 = row0 + (t >> 2), ar2 = ar1 + 64;
  const int tokA = (ar1 < cnt) ? perm_e[ar1] : 0;
  const int tokB = (ar2 < cnt) ? perm_e[ar2] : 0;
  const int kg = (t & 3) * 8;
  const float* pA1 = x + (size_t)tokA * NC + kg;
  const float* pA2 = x + (size_t)tokB * NC + kg;
  const int n0 = blockIdx.x * 128;

  const __bf16* pB1 = nullptr; const __bf16* pB2 = nullptr;  // FASTB
  const float* pBw = nullptr;                                 // !FASTB
  const int kk = t >> 3, cc = (t & 7) * 16;
  if (FASTB) {
    const __bf16* bt = (const __bf16*)bsrc;
    const int nrow = n0 + (t >> 2);
    pB1 = bt + (size_t)nrow * NC + kg;
    pB2 = bt + (size_t)(nrow + 64) * NC + kg;
  } else {
    pBw = (const float*)bsrc + (size_t)kk * NH + n0 + cc;
  }

  f32x4_t acc[4][4];
#pragma unroll
  for (int i = 0; i < 4; ++i)
#pragma unroll
    for (int j = 0; j < 4; ++j)
#pragma unroll
      for (int k = 0; k < 4; ++k) acc[i][j][k] = 0.f;

  const int lane = t & 63, wid = t >> 6;
  const int wm = (wid >> 1) * 64, wn = (wid & 1) * 64;
  const int col16 = lane & 15, quad = lane >> 4;

  if (FASTB) {
    // swizzled write slot: row r = t>>2, chunk (t&3) ^ ((r>>1)&3)
    const int woff = (t >> 2) * 32 + (((t & 3) ^ ((t >> 3) & 3)) * 8);
    // swizzled fragment read: sel invariant in mi/wm (row shifts are multiples of 16)
    const int sel = (col16 >> 1) & 3;
    const int a_off = (wm + col16) * 32 + ((quad ^ sel) * 8);
    const int b_off = (wn + col16) * 32 + ((quad ^ sel) * 8);

    float4 a1a = *(const float4*)(pA1);
    float4 a1b = *(const float4*)(pA1 + 4);
    float4 a2a = *(const float4*)(pA2);
    float4 a2b = *(const float4*)(pA2 + 4);
    uint4 vb1 = *(const uint4*)(pB1);
    uint4 vb2 = *(const uint4*)(pB2);
    int cur = 0;
    for (int k0 = 0; k0 < NC; k0 += 32) {
      __bf16* Asc = As + cur * 4096;
      __bf16* Bsc = Bs + cur * 4096;
      cvt8(a1a, a1b, Asc + woff);
      cvt8(a2a, a2b, Asc + 2048 + woff);
      *(uint4*)(Bsc + woff) = vb1;
      *(uint4*)(Bsc + 2048 + woff) = vb2;
      if (k0 + 32 < NC) {  // prefetch next K-tile; latency hides under barrier+compute
        a1a = *(const float4*)(pA1 + k0 + 32);
        a1b = *(const float4*)(pA1 + k0 + 36);
        a2a = *(const float4*)(pA2 + k0 + 32);
        a2b = *(const float4*)(pA2 + k0 + 36);
        vb1 = *(const uint4*)(pB1 + k0 + 32);
        vb2 = *(const uint4*)(pB2 + k0 + 32);
      }
      __syncthreads();  // single barrier/iter: prev iter's barrier covers WAR on buf
      bf16x8_t af[4], bfr[4];
#pragma unroll
      for (int mi = 0; mi < 4; ++mi) af[mi] = *(const bf16x8_t*)(Asc + a_off + mi * 512);
#pragma unroll
      for (int ni = 0; ni < 4; ++ni) bfr[ni] = *(const bf16x8_t*)(Bsc + b_off + ni * 512);
#pragma unroll
      for (int mi = 0; mi < 4; ++mi)
#pragma unroll
        for (int ni = 0; ni < 4; ++ni)
          acc[mi][ni] = __builtin_amdgcn_mfma_f32_16x16x32_bf16(af[mi], bfr[ni], acc[mi][ni], 0, 0, 0);
      cur ^= 1;
    }
  } else {
    // fallback: original single-buffer loop, unswizzled
    const int a_off = (wm + col16) * 32 + quad * 8;
    for (int k0 = 0; k0 < NC; k0 += 32) {
      const float4 a1a = *(const float4*)(pA1 + k0);
      const float4 a1b = *(const float4*)(pA1 + k0 + 4);
      const float4 a2a = *(const float4*)(pA2 + k0);
      const float4 a2b = *(const float4*)(pA2 + k0 + 4);
      const float* pw = pBw + (size_t)k0 * NH;
      const float4 w0 = *(const float4*)pw;
      const float4 w1 = *(const float4*)(pw + 4);
      const float4 w2 = *(const float4*)(pw + 8);
      const float4 w3 = *(const float4*)(pw + 12);
      __syncthreads();
      cvt8(a1a, a1b, As + t * 8);
      cvt8(a2a, a2b, As + 2048 + t * 8);
      cvt8(w0, w1, Bs + kk * 128 + cc);
      cvt8(w2, w3, Bs + kk * 128 + cc + 8);
      __syncthreads();
      bf16x8_t af[4], bfr[4];
#pragma unroll
      for (int mi = 0; mi < 4; ++mi) af[mi] = *(const bf16x8_t*)(As + a_off + mi * 512);
#pragma unroll
      for (int ni = 0; ni < 4; ++ni) {
        const int bn = wn + ni * 16 + col16;
#pragma unroll
        for (int j = 0; j < 8; ++j) bfr[ni][j] = Bs[(quad * 8 + j) * 128 + bn];
      }
#pragma unroll
      for (int mi = 0; mi < 4; ++mi)
#pragma unroll
        for (int ni = 0; ni < 4; ++ni)
          acc[mi][ni] = __builtin_amdgcn_mfma_f32_16x16x32_bf16(af[mi], bfr[ni], acc[mi][ni], 0, 0, 0);
    }
  }

  // C/D: col = lane&15, row = quad*4 + reg (m89-verified)
  const int colbase = n0 + wn + col16;
#pragma unroll
  for (int mi = 0; mi < 4; ++mi)
#pragma unroll
    for (int reg = 0; reg < 4; ++reg) {
      const int lr = lr0 + wm + mi * 16 + quad * 4 + reg;
      if (chunk_start + lr < cnt) {
        __bf16* hp = hbuf + (size_t)lr * NH + colbase;
#pragma unroll
        for (int ni = 0; ni < 4; ++ni) {
          const float v = acc[mi][ni][reg] + bias[colbase + ni * 16];
          hp[ni * 16] = (__bf16)fmaxf(v, 0.f);
        }
      }
    }
}

// ---------------- GEMM2: out[tok] += p * (h @ w2e + b2), fp32 out ----------------
template<bool FASTB>
__global__ __launch_bounds__(256) void moe_gemm2(
    const __bf16* __restrict__ hbuf, const void* __restrict__ bsrc,
    const float* __restrict__ bias, float* __restrict__ out,
    const int* __restrict__ counts_e, const int* __restrict__ perm_e,
    const float* __restrict__ pprob_e, int chunk_start) {
  int cnt = *counts_e; if (cnt > NN) cnt = NN; if (cnt < 0) cnt = 0;
  const int lr0 = blockIdx.y * 128;
  if (chunk_start + lr0 >= cnt) return;
  const int t = threadIdx.x;

  __shared__ __align__(16) __bf16 As[2 * 128 * 32];
  __shared__ __align__(16) __bf16 Bs[2 * 128 * 32];

  const int lar1 = lr0 + (t >> 2);
  const int kg = (t & 3) * 8;
  const __bf16* pA1 = hbuf + (size_t)lar1 * NH + kg;
  const __bf16* pA2 = pA1 + (size_t)64 * NH;
  const int n0 = blockIdx.x * 128;

  const __bf16* pB1 = nullptr; const __bf16* pB2 = nullptr;
  const float* pBw = nullptr;
  const int kk = t >> 3, cc = (t & 7) * 16;
  if (FASTB) {
    const __bf16* bt = (const __bf16*)bsrc;
    const int nrow = n0 + (t >> 2);
    pB1 = bt + (size_t)nrow * NH + kg;
    pB2 = bt + (size_t)(nrow + 64) * NH + kg;
  } else {
    pBw = (const float*)bsrc + (size_t)kk * NC + n0 + cc;
  }

  f32x4_t acc[4][4];
#pragma unroll
  for (int i = 0; i < 4; ++i)
#pragma unroll
    for (int j = 0; j < 4; ++j)
#pragma unroll
      for (int k = 0; k < 4; ++k) acc[i][j][k] = 0.f;

  const int lane = t & 63, wid = t >> 6;
  const int wm = (wid >> 1) * 64, wn = (wid & 1) * 64;
  const int col16 = lane & 15, quad = lane >> 4;

  if (FASTB) {
    const int woff = (t >> 2) * 32 + (((t & 3) ^ ((t >> 3) & 3)) * 8);
    const int sel = (col16 >> 1) & 3;
    const int a_off = (wm + col16) * 32 + ((quad ^ sel) * 8);
    const int b_off = (wn + col16) * 32 + ((quad ^ sel) * 8);

    uint4 va1 = *(const uint4*)(pA1);
    uint4 va2 = *(const uint4*)(pA2);
    uint4 vb1 = *(const uint4*)(pB1);
    uint4 vb2 = *(const uint4*)(pB2);
    int cur = 0;
    for (int k0 = 0; k0 < NH; k0 += 32) {
      __bf16* Asc = As + cur * 4096;
      __bf16* Bsc = Bs + cur * 4096;
      *(uint4*)(Asc + woff) = va1;
      *(uint4*)(Asc + 2048 + woff) = va2;
      *(uint4*)(Bsc + woff) = vb1;
      *(uint4*)(Bsc + 2048 + woff) = vb2;
      if (k0 + 32 < NH) {
        va1 = *(const uint4*)(pA1 + k0 + 32);
        va2 = *(const uint4*)(pA2 + k0 + 32);
        vb1 = *(const uint4*)(pB1 + k0 + 32);
        vb2 = *(const uint4*)(pB2 + k0 + 32);
      }
      __syncthreads();
      bf16x8_t af[4], bfr[4];
#pragma unroll
      for (int mi = 0; mi < 4; ++mi) af[mi] = *(const bf16x8_t*)(Asc + a_off + mi * 512);
#pragma unroll
      for (int ni = 0; ni < 4; ++ni) bfr[ni] = *(const bf16x8_t*)(Bsc + b_off + ni * 512);
#pragma unroll
      for (int mi = 0; mi < 4; ++mi)
#pragma unroll
        for (int ni = 0; ni < 4; ++ni)
          acc[mi][ni] = __builtin_amdgcn_mfma_f32_16x16x32_bf16(af[mi], bfr[ni], acc[mi][ni], 0, 0, 0);
      cur ^= 1;
    }
  } else {
    const int a_off = (wm + col16) * 32 + quad * 8;
    for (int k0 = 0; k0 < NH; k0 += 32) {
      const uint4 va1 = *(const uint4*)(pA1 + k0);
      const uint4 va2 = *(const uint4*)(pA2 + k0);
      const float* pw = pBw + (size_t)k0 * NC;
      const float4 w0 = *(const float4*)pw;
      const float4 w1 = *(const float4*)(pw + 4);
      const float4 w2 = *(const float4*)(pw + 8);
      const float4 w3 = *(const float4*)(pw + 12);
      __syncthreads();
      *(uint4*)(As + t * 8) = va1;
      *(uint4*)(As + 2048 + t * 8) = va2;
      cvt8(w0, w1, Bs + kk * 128 + cc);
      cvt8(w2, w3, Bs + kk * 128 + cc + 8);
      __syncthreads();
      bf16x8_t af[4], bfr[4];
#pragma unroll
      for (int mi = 0; mi < 4; ++mi) af[mi] = *(const bf16x8_t*)(As + a_off + mi * 512);
#pragma unroll
      for (int ni = 0; ni < 4; ++ni) {
        const int bn = wn + ni * 16 + col16;
#pragma unroll
        for (int j = 0; j < 8; ++j) bfr[ni][j] = Bs[(quad * 8 + j) * 128 + bn];
      }
#pragma unroll
      for (int mi = 0; mi < 4; ++mi)
#pragma unroll
        for (int ni = 0; ni < 4; ++ni)
          acc[mi][ni] = __builtin_amdgcn_mfma_f32_16x16x32_bf16(af[mi], bfr[ni], acc[mi][ni], 0, 0, 0);
    }
  }

  const int colbase = n0 + wn + col16;
#pragma unroll
  for (int mi = 0; mi < 4; ++mi)
#pragma unroll
    for (int reg = 0; reg < 4; ++reg) {
      const int lr = lr0 + wm + mi * 16 + quad * 4 + reg;
      const int r = chunk_start + lr;
      if (r < cnt) {
        const int tok = perm_e[r];
        const float p = pprob_e[r];
        float* op = out + (size_t)tok * NC + colbase;
#pragma unroll
        for (int ni = 0; ni < 4; ++ni) {
          op[ni * 16] += (acc[mi][ni][reg] + bias[colbase + ni * 16]) * p;  // one writer per (tok,col) per launch
        }
      }
    }
}

extern "C" void kernel_launch(void* const* d_in, const int* in_sizes, int n_in,
                              void* d_out, int out_size, void* d_ws, size_t ws_size,
                              hipStream_t stream) {
  (void)in_sizes; (void)n_in;
  const float* x   = (const float*)d_in[0];
  const float* eps = (const float*)d_in[1];
  const float* rw  = (const float*)d_in[2];
  const float* rb  = (const float*)d_in[3];
  const float* nw  = (const float*)d_in[4];
  const float* nb  = (const float*)d_in[5];
  const float* w1  = (const float*)d_in[6];
  const float* b1  = (const float*)d_in[7];
  const float* w2  = (const float*)d_in[8];
  const float* b2  = (const float*)d_in[9];
  float* out = (float*)d_out;

  // ws: counts(256B) | perm [E][N] | pprob [E][N] | eidx [N] | pp2 [N] | {w1t, w2t bf16 if fast} | hbuf bf16
  char* wsb = (char*)d_ws;
  int* counts = (int*)wsb;
  int* perm = (int*)(wsb + 256);
  float* pprob = (float*)(wsb + 256 + (size_t)NE * NN * 4);
  int* eidx = (int*)(wsb + 256 + (size_t)NE * NN * 8);
  float2* pp2 = (float2*)(wsb + 256 + (size_t)NE * NN * 8 + (size_t)NN * 4);
  size_t off = 256 + (size_t)NE * NN * 8 + (size_t)NN * 12;  // ~1.25 MB

  const size_t wtile = (size_t)NC * NH * 2;  // 8 MB per transposed weight
  const bool fast = ws_size >= off + 2 * wtile + (size_t)128 * NH * 2 + (1u << 20);
  __bf16* w1t = nullptr; __bf16* w2t = nullptr;
  if (fast) {
    w1t = (__bf16*)(wsb + off); off += wtile;
    w2t = (__bf16*)(wsb + off); off += wtile;
  }
  __bf16* hbuf = (__bf16*)(wsb + off);
  const size_t remain = (ws_size > off) ? (ws_size - off) : 0;
  long rows_cap = (long)(remain / ((size_t)NH * 2));
  rows_cap = (rows_cap / 128) * 128;
  if (rows_cap > NN) rows_cap = NN;
  if (rows_cap < 128) rows_cap = 128;  // floor; needs ws >= ~2.3 MB

  hipMemsetAsync(counts, 0, 256, stream);
  hipMemsetAsync(d_out, 0, (size_t)out_size * 4, stream);

  routing_kernel<<<NN / 4, 256, 0, stream>>>(x, eps, rw, rb, nw, nb, eidx, pp2);
  build_lists<<<NN / 256, 256, 0, stream>>>(eidx, pp2, counts, perm, pprob);

  const int nchunks = (int)((NN + rows_cap - 1) / rows_cap);
  for (int e = 0; e < NE; ++e) {
    const float* w1e = w1 + (size_t)e * NC * NH;  // [C][H] fp32
    const float* w2e = w2 + (size_t)e * NH * NC;  // [H][C] fp32
    if (fast) {
      transpose_cvt<<<dim3(NH / 64, NC / 64), 256, 0, stream>>>(w1e, w1t, NC, NH);
      transpose_cvt<<<dim3(NC / 64, NH / 64), 256, 0, stream>>>(w2e, w2t, NH, NC);
    }
    for (int ch = 0; ch < nchunks; ++ch) {
      const int cs = ch * (int)rows_cap;
      if (fast) {
        moe_gemm1<true><<<dim3(NH / 128, (unsigned)(rows_cap / 128)), 256, 0, stream>>>(
            x, w1t, b1 + (size_t)e * NH, hbuf, counts + e, perm + (size_t)e * NN, cs);
        moe_gemm2<true><<<dim3(NC / 128, (unsigned)(rows_cap / 128)), 256, 0, stream>>>(
            hbuf, w2t, b2 + (size_t)e * NC, out, counts + e, perm + (size_t)e * NN,
            pprob + (size_t)e * NN, cs);
      } else {
        moe_gemm1<false><<<dim3(NH / 128, (unsigned)(rows_cap / 128)), 256, 0, stream>>>(
            x, w1e, b1 + (size_t)e * NH, hbuf, counts + e, perm + (size_t)e * NN, cs);
        moe_gemm2<false><<<dim3(NC / 128, (unsigned)(rows_cap / 128)), 256, 0, stream>>>(
            hbuf, w2e, b2 + (size_t)e * NC, out, counts + e, perm + (size_t)e * NN,
            pprob + (size_t)e * NN, cs);
      }
    }
  }
}

// Round 6
// 1658.739 us; speedup vs baseline: 1.3263x; 1.0353x over previous
//
#include <hip/hip_runtime.h>
#include <hip/hip_bf16.h>
#include <stdint.h>

// Problem constants (SparseMoE: B=4, T=4096, C=1024, E=8, H=4C, topk=2)
#define NC 1024
#define NE 8
#define NH 4096
#define NN 16384   // B*T tokens

typedef __bf16 bf16x8_t __attribute__((ext_vector_type(8)));
typedef float f32x4_t __attribute__((ext_vector_type(4)));

// Convert 8 fp32 -> 8 bf16, write 16B to LDS/global.
__device__ __forceinline__ void cvt8(const float4 a, const float4 b, __bf16* dst) {
  bf16x8_t r;
  r[0] = (__bf16)a.x; r[1] = (__bf16)a.y; r[2] = (__bf16)a.z; r[3] = (__bf16)a.w;
  r[4] = (__bf16)b.x; r[5] = (__bf16)b.y; r[6] = (__bf16)b.z; r[7] = (__bf16)b.w;
  *(bf16x8_t*)dst = r;
}

// One 128x128x32 MFMA step from swizzled LDS tiles.
__device__ __forceinline__ void mfma_step(const __bf16* __restrict__ Asc,
    const __bf16* __restrict__ Bsc, int a_off, int b_off, f32x4_t (&acc)[4][4]) {
  bf16x8_t af[4], bfr[4];
#pragma unroll
  for (int mi = 0; mi < 4; ++mi) af[mi] = *(const bf16x8_t*)(Asc + a_off + mi * 512);
#pragma unroll
  for (int ni = 0; ni < 4; ++ni) bfr[ni] = *(const bf16x8_t*)(Bsc + b_off + ni * 512);
#pragma unroll
  for (int mi = 0; mi < 4; ++mi)
#pragma unroll
    for (int ni = 0; ni < 4; ++ni)
      acc[mi][ni] = __builtin_amdgcn_mfma_f32_16x16x32_bf16(af[mi], bfr[ni], acc[mi][ni], 0, 0, 0);
}

// ---------------- routing phase A (fp32 exact, double accum): noisy top-2 + probs per token.
__global__ __launch_bounds__(256) void routing_kernel(
    const float* __restrict__ x, const float* __restrict__ eps,
    const float* __restrict__ rw, const float* __restrict__ rb,
    const float* __restrict__ nw, const float* __restrict__ nb,
    int* __restrict__ eidx, float2* __restrict__ pp2) {
  const int lane = threadIdx.x & 63;
  const int n = blockIdx.x * 4 + (threadIdx.x >> 6);  // one wave per token
  if (n >= NN) return;
  double acc[16];
#pragma unroll
  for (int i = 0; i < 16; ++i) acc[i] = 0.0;
  const float* xr = x + (size_t)n * NC;
  for (int c0 = 0; c0 < NC; c0 += 64) {
    const int c = c0 + lane;
    const float xv = xr[c];
    const float4 r0 = *(const float4*)(rw + (size_t)c * NE);
    const float4 r1 = *(const float4*)(rw + (size_t)c * NE + 4);
    const float4 n0 = *(const float4*)(nw + (size_t)c * NE);
    const float4 n1 = *(const float4*)(nw + (size_t)c * NE + 4);
    acc[0] += (double)xv * r0.x;  acc[1] += (double)xv * r0.y;
    acc[2] += (double)xv * r0.z;  acc[3] += (double)xv * r0.w;
    acc[4] += (double)xv * r1.x;  acc[5] += (double)xv * r1.y;
    acc[6] += (double)xv * r1.z;  acc[7] += (double)xv * r1.w;
    acc[8] += (double)xv * n0.x;  acc[9] += (double)xv * n0.y;
    acc[10] += (double)xv * n0.z; acc[11] += (double)xv * n0.w;
    acc[12] += (double)xv * n1.x; acc[13] += (double)xv * n1.y;
    acc[14] += (double)xv * n1.z; acc[15] += (double)xv * n1.w;
  }
#pragma unroll
  for (int off = 32; off > 0; off >>= 1) {
#pragma unroll
    for (int i = 0; i < 16; ++i) acc[i] += __shfl_xor(acc[i], off, 64);
  }
  if (lane == 0) {
    double noisy[NE];
#pragma unroll
    for (int e = 0; e < NE; ++e) {
      const double lg = acc[e] + (double)rb[e];
      const double z = acc[8 + e] + (double)nb[e];
      const double sp = log1p(exp(-fabs(z))) + fmax(z, 0.0);  // stable softplus
      noisy[e] = lg + (double)eps[(size_t)n * NE + e] * sp;
    }
    int i1 = -1, i2 = -1;
    double v1 = -1e300, v2 = -1e300;
#pragma unroll
    for (int e = 0; e < NE; ++e) {  // strict > keeps earlier index on ties (lax.top_k)
      const double v = noisy[e];
      if (v > v1) { v2 = v1; i2 = i1; v1 = v; i1 = e; }
      else if (v > v2) { v2 = v; i2 = e; }
    }
    if (i1 < 0) i1 = 0;                       // hardening vs pathological inputs
    if (i2 < 0 || i2 == i1) i2 = (i1 + 1) & 7;
    const double d = exp(v2 - v1);
    const float p1 = (float)(1.0 / (1.0 + d));
    const float p2 = (float)(d / (1.0 + d));
    eidx[n] = i1 | (i2 << 8);
    pp2[n] = float2{p1, p2};
  }
}

// ---------------- routing phase B: per-expert token lists, block-aggregated atomics.
__global__ __launch_bounds__(256) void build_lists(
    const int* __restrict__ eidx, const float2* __restrict__ pp2,
    int* __restrict__ counts, int* __restrict__ perm, float* __restrict__ pprob) {
  __shared__ int hist[NE];
  __shared__ int base[NE];
  const int t = threadIdx.x;
  if (t < NE) hist[t] = 0;
  __syncthreads();
  const int n = blockIdx.x * 256 + t;
  const int packed = eidx[n];
  const int e1 = packed & 255;
  const int e2 = (packed >> 8) & 255;
  const float2 p = pp2[n];
  const int l1 = atomicAdd(&hist[e1], 1);   // LDS atomic: within-block rank
  const int l2 = atomicAdd(&hist[e2], 1);
  __syncthreads();
  if (t < NE) base[t] = atomicAdd(&counts[t], hist[t]);
  __syncthreads();
  const int o1 = base[e1] + l1;
  const int o2 = base[e2] + l2;
  perm[e1 * NN + o1] = n; pprob[e1 * NN + o1] = p.x;
  perm[e2 * NN + o2] = n; pprob[e2 * NN + o2] = p.y;
}

// ---------------- transpose + fp32->bf16: src fp32 [R][Cc] -> dst bf16 [Cc][R] ----------------
// blockIdx.z selects the expert (matrix stride R*Cc); launch z=1 for single-expert mode.
__global__ __launch_bounds__(256) void transpose_cvt(
    const float* __restrict__ src, __bf16* __restrict__ dst, int R, int Cc) {
  const size_t mat = (size_t)R * Cc;
  src += (size_t)blockIdx.z * mat;
  dst += (size_t)blockIdx.z * mat;
  __shared__ __align__(16) __bf16 tile[64][72];  // +8 pad
  const int r0 = blockIdx.y * 64, c0 = blockIdx.x * 64;
  const int t = threadIdx.x;
  const int tr = t >> 3;            // 0..31
  const int tc = (t & 7) * 8;       // 0..56
#pragma unroll
  for (int h = 0; h < 2; ++h) {
    const int r = tr + h * 32;
    const float* sp = src + (size_t)(r0 + r) * Cc + (c0 + tc);
    const float4 a = *(const float4*)sp;
    const float4 b = *(const float4*)(sp + 4);
    cvt8(a, b, &tile[r][tc]);
  }
  __syncthreads();
#pragma unroll
  for (int h = 0; h < 2; ++h) {
    const int c = tr + h * 32;
    __bf16 tmp[8] __attribute__((aligned(16)));
#pragma unroll
    for (int j = 0; j < 8; ++j) tmp[j] = tile[tc + j][c];
    __bf16* dp = dst + (size_t)(c0 + c) * R + (r0 + tc);
    *(uint4*)dp = *(const uint4*)tmp;
  }
}

// LDS tile geometry (FASTB path, both GEMMs):
//   As/Bs: 128 rows x 32 k bf16 (64 B rows), T2 XOR-swizzle chunk' = chunk ^ ((r>>1)&3)
//   -> ds_read_b128 conflict-free (verified: SQ_LDS_BANK_CONFLICT 4.46M -> 0 in R4).
//   Depth-2 register prefetch + unroll-by-2 K-loop: loads issued a full 64-K body
//   (~700-900 cyc) ahead of their s_waitcnt; one barrier per 32-K.

// ---------------- GEMM1: h = relu(gather(x) @ w1e + b1), bf16 MFMA ----------------
template<bool FASTB>
__global__ __launch_bounds__(256) void moe_gemm1(
    const float* __restrict__ x, const void* __restrict__ bsrc,
    const float* __restrict__ bias, __bf16* __restrict__ hbuf,
    const int* __restrict__ counts_e, const int* __restrict__ perm_e, int chunk_start) {
  int cnt = *counts_e; if (cnt > NN) cnt = NN; if (cnt < 0) cnt = 0;
  const int lr0 = blockIdx.y * 128;
  const int row0 = chunk_start + lr0;
  if (row0 >= cnt) return;
  const int t = threadIdx.x;

  __shared__ __align__(16) __bf16 As[2 * 128 * 32];
  __shared__ __align__(16) __bf16 Bs[2 * 128 * 32];

  const int ar1 = row0 + (t >> 2), ar2 = ar1 + 64;
  const int tokA = (ar1 < cnt) ? perm_e[ar1] : 0;
  const int tokB = (ar2 < cnt) ? perm_e[ar2] : 0;
  const int kg = (t & 3) * 8;
  const float* pA1 = x + (size_t)tokA * NC + kg;
  const float* pA2 = x + (size_t)tokB * NC + kg;
  const int n0 = blockIdx.x * 128;

  const __bf16* pB1 = nullptr; const __bf16* pB2 = nullptr;  // FASTB
  const float* pBw = nullptr;                                 // !FASTB
  const int kk = t >> 3, cc = (t & 7) * 16;
  if (FASTB) {
    const __bf16* bt = (const __bf16*)bsrc;
    const int nrow = n0 + (t >> 2);
    pB1 = bt + (size_t)nrow * NC + kg;
    pB2 = bt + (size_t)(nrow + 64) * NC + kg;
  } else {
    pBw = (const float*)bsrc + (size_t)kk * NH + n0 + cc;
  }

  f32x4_t acc[4][4];
#pragma unroll
  for (int i = 0; i < 4; ++i)
#pragma unroll
    for (int j = 0; j < 4; ++j)
#pragma unroll
      for (int k = 0; k < 4; ++k) acc[i][j][k] = 0.f;

  const int lane = t & 63, wid = t >> 6;
  const int wm = (wid >> 1) * 64, wn = (wid & 1) * 64;
  const int col16 = lane & 15, quad = lane >> 4;

  if (FASTB) {
    const int woff = (t >> 2) * 32 + (((t & 3) ^ ((t >> 3) & 3)) * 8);
    const int sel = (col16 >> 1) & 3;
    const int a_off = (wm + col16) * 32 + ((quad ^ sel) * 8);
    const int b_off = (wn + col16) * 32 + ((quad ^ sel) * 8);
    __bf16* As0 = As; __bf16* As1 = As + 4096;
    __bf16* Bs0 = Bs; __bf16* Bs1 = Bs + 4096;

    // depth-2 prefetch: two named register sets (no runtime-indexed arrays)
    float4 a1a0 = *(const float4*)(pA1),      a1b0 = *(const float4*)(pA1 + 4);
    float4 a2a0 = *(const float4*)(pA2),      a2b0 = *(const float4*)(pA2 + 4);
    uint4  vb10 = *(const uint4*)(pB1),       vb20 = *(const uint4*)(pB2);
    float4 a1a1 = *(const float4*)(pA1 + 32), a1b1 = *(const float4*)(pA1 + 36);
    float4 a2a1 = *(const float4*)(pA2 + 32), a2b1 = *(const float4*)(pA2 + 36);
    uint4  vb11 = *(const uint4*)(pB1 + 32),  vb21 = *(const uint4*)(pB2 + 32);

    for (int k0 = 0; k0 < NC; k0 += 64) {
      // ---- half 0: write buf0 from set0, refill set0 for k0+64 ----
      cvt8(a1a0, a1b0, As0 + woff);
      cvt8(a2a0, a2b0, As0 + 2048 + woff);
      *(uint4*)(Bs0 + woff) = vb10;
      *(uint4*)(Bs0 + 2048 + woff) = vb20;
      {
        const int kn = (k0 + 64 < NC) ? k0 + 64 : 0;  // clamp: dummy-load, unused
        a1a0 = *(const float4*)(pA1 + kn); a1b0 = *(const float4*)(pA1 + kn + 4);
        a2a0 = *(const float4*)(pA2 + kn); a2b0 = *(const float4*)(pA2 + kn + 4);
        vb10 = *(const uint4*)(pB1 + kn);  vb20 = *(const uint4*)(pB2 + kn);
      }
      __syncthreads();   // buf0 ready; also fences prev half-1 reads vs this write
      mfma_step(As0, Bs0, a_off, b_off, acc);
      // ---- half 1: write buf1 from set1, refill set1 for k0+96 ----
      cvt8(a1a1, a1b1, As1 + woff);
      cvt8(a2a1, a2b1, As1 + 2048 + woff);
      *(uint4*)(Bs1 + woff) = vb11;
      *(uint4*)(Bs1 + 2048 + woff) = vb21;
      {
        const int kn = (k0 + 96 < NC) ? k0 + 96 : 0;
        a1a1 = *(const float4*)(pA1 + kn); a1b1 = *(const float4*)(pA1 + kn + 4);
        a2a1 = *(const float4*)(pA2 + kn); a2b1 = *(const float4*)(pA2 + kn + 4);
        vb11 = *(const uint4*)(pB1 + kn);  vb21 = *(const uint4*)(pB2 + kn);
      }
      __syncthreads();
      mfma_step(As1, Bs1, a_off, b_off, acc);
    }
  } else {
    // fallback: original single-buffer loop, unswizzled
    const int a_off = (wm + col16) * 32 + quad * 8;
    for (int k0 = 0; k0 < NC; k0 += 32) {
      const float4 a1a = *(const float4*)(pA1 + k0);
      const float4 a1b = *(const float4*)(pA1 + k0 + 4);
      const float4 a2a = *(const float4*)(pA2 + k0);
      const float4 a2b = *(const float4*)(pA2 + k0 + 4);
      const float* pw = pBw + (size_t)k0 * NH;
      const float4 w0 = *(const float4*)pw;
      const float4 w1 = *(const float4*)(pw + 4);
      const float4 w2 = *(const float4*)(pw + 8);
      const float4 w3 = *(const float4*)(pw + 12);
      __syncthreads();
      cvt8(a1a, a1b, As + t * 8);
      cvt8(a2a, a2b, As + 2048 + t * 8);
      cvt8(w0, w1, Bs + kk * 128 + cc);
      cvt8(w2, w3, Bs + kk * 128 + cc + 8);
      __syncthreads();
      bf16x8_t af[4], bfr[4];
#pragma unroll
      for (int mi = 0; mi < 4; ++mi) af[mi] = *(const bf16x8_t*)(As + a_off + mi * 512);
#pragma unroll
      for (int ni = 0; ni < 4; ++ni) {
        const int bn = wn + ni * 16 + col16;
#pragma unroll
        for (int j = 0; j < 8; ++j) bfr[ni][j] = Bs[(quad * 8 + j) * 128 + bn];
      }
#pragma unroll
      for (int mi = 0; mi < 4; ++mi)
#pragma unroll
        for (int ni = 0; ni < 4; ++ni)
          acc[mi][ni] = __builtin_amdgcn_mfma_f32_16x16x32_bf16(af[mi], bfr[ni], acc[mi][ni], 0, 0, 0);
    }
  }

  // C/D: col = lane&15, row = quad*4 + reg (m89-verified)
  const int colbase = n0 + wn + col16;
#pragma unroll
  for (int mi = 0; mi < 4; ++mi)
#pragma unroll
    for (int reg = 0; reg < 4; ++reg) {
      const int lr = lr0 + wm + mi * 16 + quad * 4 + reg;
      if (chunk_start + lr < cnt) {
        __bf16* hp = hbuf + (size_t)lr * NH + colbase;
#pragma unroll
        for (int ni = 0; ni < 4; ++ni) {
          const float v = acc[mi][ni][reg] + bias[colbase + ni * 16];
          hp[ni * 16] = (__bf16)fmaxf(v, 0.f);
        }
      }
    }
}

// ---------------- GEMM2: out[tok] += p * (h @ w2e + b2), fp32 out ----------------
template<bool FASTB>
__global__ __launch_bounds__(256) void moe_gemm2(
    const __bf16* __restrict__ hbuf, const void* __restrict__ bsrc,
    const float* __restrict__ bias, float* __restrict__ out,
    const int* __restrict__ counts_e, const int* __restrict__ perm_e,
    const float* __restrict__ pprob_e, int chunk_start) {
  int cnt = *counts_e; if (cnt > NN) cnt = NN; if (cnt < 0) cnt = 0;
  const int lr0 = blockIdx.y * 128;
  if (chunk_start + lr0 >= cnt) return;
  const int t = threadIdx.x;

  __shared__ __align__(16) __bf16 As[2 * 128 * 32];
  __shared__ __align__(16) __bf16 Bs[2 * 128 * 32];

  const int lar1 = lr0 + (t >> 2);
  const int kg = (t & 3) * 8;
  const __bf16* pA1 = hbuf + (size_t)lar1 * NH + kg;
  const __bf16* pA2 = pA1 + (size_t)64 * NH;
  const int n0 = blockIdx.x * 128;

  const __bf16* pB1 = nullptr; const __bf16* pB2 = nullptr;
  const float* pBw = nullptr;
  const int kk = t >> 3, cc = (t & 7) * 16;
  if (FASTB) {
    const __bf16* bt = (const __bf16*)bsrc;
    const int nrow = n0 + (t >> 2);
    pB1 = bt + (size_t)nrow * NH + kg;
    pB2 = bt + (size_t)(nrow + 64) * NH + kg;
  } else {
    pBw = (const float*)bsrc + (size_t)kk * NC + n0 + cc;
  }

  f32x4_t acc[4][4];
#pragma unroll
  for (int i = 0; i < 4; ++i)
#pragma unroll
    for (int j = 0; j < 4; ++j)
#pragma unroll
      for (int k = 0; k < 4; ++k) acc[i][j][k] = 0.f;

  const int lane = t & 63, wid = t >> 6;
  const int wm = (wid >> 1) * 64, wn = (wid & 1) * 64;
  const int col16 = lane & 15, quad = lane >> 4;

  if (FASTB) {
    const int woff = (t >> 2) * 32 + (((t & 3) ^ ((t >> 3) & 3)) * 8);
    const int sel = (col16 >> 1) & 3;
    const int a_off = (wm + col16) * 32 + ((quad ^ sel) * 8);
    const int b_off = (wn + col16) * 32 + ((quad ^ sel) * 8);
    __bf16* As0 = As; __bf16* As1 = As + 4096;
    __bf16* Bs0 = Bs; __bf16* Bs1 = Bs + 4096;

    uint4 va10 = *(const uint4*)(pA1),      va20 = *(const uint4*)(pA2);
    uint4 vb10 = *(const uint4*)(pB1),      vb20 = *(const uint4*)(pB2);
    uint4 va11 = *(const uint4*)(pA1 + 32), va21 = *(const uint4*)(pA2 + 32);
    uint4 vb11 = *(const uint4*)(pB1 + 32), vb21 = *(const uint4*)(pB2 + 32);

    for (int k0 = 0; k0 < NH; k0 += 64) {
      // ---- half 0 ----
      *(uint4*)(As0 + woff) = va10;
      *(uint4*)(As0 + 2048 + woff) = va20;
      *(uint4*)(Bs0 + woff) = vb10;
      *(uint4*)(Bs0 + 2048 + woff) = vb20;
      {
        const int kn = (k0 + 64 < NH) ? k0 + 64 : 0;
        va10 = *(const uint4*)(pA1 + kn); va20 = *(const uint4*)(pA2 + kn);
        vb10 = *(const uint4*)(pB1 + kn); vb20 = *(const uint4*)(pB2 + kn);
      }
      __syncthreads();
      mfma_step(As0, Bs0, a_off, b_off, acc);
      // ---- half 1 ----
      *(uint4*)(As1 + woff) = va11;
      *(uint4*)(As1 + 2048 + woff) = va21;
      *(uint4*)(Bs1 + woff) = vb11;
      *(uint4*)(Bs1 + 2048 + woff) = vb21;
      {
        const int kn = (k0 + 96 < NH) ? k0 + 96 : 0;
        va11 = *(const uint4*)(pA1 + kn); va21 = *(const uint4*)(pA2 + kn);
        vb11 = *(const uint4*)(pB1 + kn); vb21 = *(const uint4*)(pB2 + kn);
      }
      __syncthreads();
      mfma_step(As1, Bs1, a_off, b_off, acc);
    }
  } else {
    const int a_off = (wm + col16) * 32 + quad * 8;
    for (int k0 = 0; k0 < NH; k0 += 32) {
      const uint4 va1 = *(const uint4*)(pA1 + k0);
      const uint4 va2 = *(const uint4*)(pA2 + k0);
      const float* pw = pBw + (size_t)k0 * NC;
      const float4 w0 = *(const float4*)pw;
      const float4 w1 = *(const float4*)(pw + 4);
      const float4 w2 = *(const float4*)(pw + 8);
      const float4 w3 = *(const float4*)(pw + 12);
      __syncthreads();
      *(uint4*)(As + t * 8) = va1;
      *(uint4*)(As + 2048 + t * 8) = va2;
      cvt8(w0, w1, Bs + kk * 128 + cc);
      cvt8(w2, w3, Bs + kk * 128 + cc + 8);
      __syncthreads();
      bf16x8_t af[4], bfr[4];
#pragma unroll
      for (int mi = 0; mi < 4; ++mi) af[mi] = *(const bf16x8_t*)(As + a_off + mi * 512);
#pragma unroll
      for (int ni = 0; ni < 4; ++ni) {
        const int bn = wn + ni * 16 + col16;
#pragma unroll
        for (int j = 0; j < 8; ++j) bfr[ni][j] = Bs[(quad * 8 + j) * 128 + bn];
      }
#pragma unroll
      for (int mi = 0; mi < 4; ++mi)
#pragma unroll
        for (int ni = 0; ni < 4; ++ni)
          acc[mi][ni] = __builtin_amdgcn_mfma_f32_16x16x32_bf16(af[mi], bfr[ni], acc[mi][ni], 0, 0, 0);
    }
  }

  const int colbase = n0 + wn + col16;
#pragma unroll
  for (int mi = 0; mi < 4; ++mi)
#pragma unroll
    for (int reg = 0; reg < 4; ++reg) {
      const int lr = lr0 + wm + mi * 16 + quad * 4 + reg;
      const int r = chunk_start + lr;
      if (r < cnt) {
        const int tok = perm_e[r];
        const float p = pprob_e[r];
        float* op = out + (size_t)tok * NC + colbase;
#pragma unroll
        for (int ni = 0; ni < 4; ++ni) {
          op[ni * 16] += (acc[mi][ni][reg] + bias[colbase + ni * 16]) * p;  // one writer per (tok,col) per launch
        }
      }
    }
}

extern "C" void kernel_launch(void* const* d_in, const int* in_sizes, int n_in,
                              void* d_out, int out_size, void* d_ws, size_t ws_size,
                              hipStream_t stream) {
  (void)in_sizes; (void)n_in;
  const float* x   = (const float*)d_in[0];
  const float* eps = (const float*)d_in[1];
  const float* rw  = (const float*)d_in[2];
  const float* rb  = (const float*)d_in[3];
  const float* nw  = (const float*)d_in[4];
  const float* nb  = (const float*)d_in[5];
  const float* w1  = (const float*)d_in[6];
  const float* b1  = (const float*)d_in[7];
  const float* w2  = (const float*)d_in[8];
  const float* b2  = (const float*)d_in[9];
  float* out = (float*)d_out;

  // ws: counts(256B) | perm [E][N] | pprob [E][N] | eidx [N] | pp2 [N] | weights bf16 | hbuf bf16
  char* wsb = (char*)d_ws;
  int* counts = (int*)wsb;
  int* perm = (int*)(wsb + 256);
  float* pprob = (float*)(wsb + 256 + (size_t)NE * NN * 4);
  int* eidx = (int*)(wsb + 256 + (size_t)NE * NN * 8);
  float2* pp2 = (float2*)(wsb + 256 + (size_t)NE * NN * 8 + (size_t)NN * 4);
  size_t off = 256 + (size_t)NE * NN * 8 + (size_t)NN * 12;  // ~1.25 MB

  const size_t wtile = (size_t)NC * NH * 2;   // 8 MB per transposed weight matrix
  const size_t hfull = (size_t)NN * NH * 2;   // 128 MB full hbuf
  // fast2: all-expert transposed weights upfront (2 transpose launches instead of 16)
  const bool fast2 = ws_size >= off + 2 * NE * wtile + hfull + (4u << 20);
  const bool fast = fast2 ||
      ws_size >= off + 2 * wtile + (size_t)128 * NH * 2 + (1u << 20);
  __bf16* w1t = nullptr; __bf16* w2t = nullptr;
  if (fast2) {
    w1t = (__bf16*)(wsb + off); off += NE * wtile;
    w2t = (__bf16*)(wsb + off); off += NE * wtile;
  } else if (fast) {
    w1t = (__bf16*)(wsb + off); off += wtile;
    w2t = (__bf16*)(wsb + off); off += wtile;
  }
  __bf16* hbuf = (__bf16*)(wsb + off);
  const size_t remain = (ws_size > off) ? (ws_size - off) : 0;
  long rows_cap = (long)(remain / ((size_t)NH * 2));
  rows_cap = (rows_cap / 128) * 128;
  if (rows_cap > NN) rows_cap = NN;
  if (rows_cap < 128) rows_cap = 128;  // floor; needs ws >= ~2.3 MB

  hipMemsetAsync(counts, 0, 256, stream);
  hipMemsetAsync(d_out, 0, (size_t)out_size * 4, stream);

  routing_kernel<<<NN / 4, 256, 0, stream>>>(x, eps, rw, rb, nw, nb, eidx, pp2);
  build_lists<<<NN / 256, 256, 0, stream>>>(eidx, pp2, counts, perm, pprob);

  if (fast2) {  // all experts in 2 launches (blockIdx.z = expert)
    transpose_cvt<<<dim3(NH / 64, NC / 64, NE), 256, 0, stream>>>(w1, w1t, NC, NH);
    transpose_cvt<<<dim3(NC / 64, NH / 64, NE), 256, 0, stream>>>(w2, w2t, NH, NC);
  }

  const int nchunks = (int)((NN + rows_cap - 1) / rows_cap);
  for (int e = 0; e < NE; ++e) {
    const float* w1e = w1 + (size_t)e * NC * NH;  // [C][H] fp32
    const float* w2e = w2 + (size_t)e * NH * NC;  // [H][C] fp32
    const __bf16* w1te = fast2 ? (w1t + (size_t)e * NC * NH) : w1t;
    const __bf16* w2te = fast2 ? (w2t + (size_t)e * NH * NC) : w2t;
    if (fast && !fast2) {
      transpose_cvt<<<dim3(NH / 64, NC / 64, 1), 256, 0, stream>>>(w1e, w1t, NC, NH);
      transpose_cvt<<<dim3(NC / 64, NH / 64, 1), 256, 0, stream>>>(w2e, w2t, NH, NC);
    }
    for (int ch = 0; ch < nchunks; ++ch) {
      const int cs = ch * (int)rows_cap;
      if (fast) {
        moe_gemm1<true><<<dim3(NH / 128, (unsigned)(rows_cap / 128)), 256, 0, stream>>>(
            x, w1te, b1 + (size_t)e * NH, hbuf, counts + e, perm + (size_t)e * NN, cs);
        moe_gemm2<true><<<dim3(NC / 128, (unsigned)(rows_cap / 128)), 256, 0, stream>>>(
            hbuf, w2te, b2 + (size_t)e * NC, out, counts + e, perm + (size_t)e * NN,
            pprob + (size_t)e * NN, cs);
      } else {
        moe_gemm1<false><<<dim3(NH / 128, (unsigned)(rows_cap / 128)), 256, 0, stream>>>(
            x, w1e, b1 + (size_t)e * NH, hbuf, counts + e, perm + (size_t)e * NN, cs);
        moe_gemm2<false><<<dim3(NC / 128, (unsigned)(rows_cap / 128)), 256, 0, stream>>>(
            hbuf, w2e, b2 + (size_t)e * NC, out, counts + e, perm + (size_t)e * NN,
            pprob + (size_t)e * NN, cs);
      }
    }
  }
}

// Round 8
// 1532.547 us; speedup vs baseline: 1.4356x; 1.0823x over previous
//
#include <hip/hip_runtime.h>
#include <hip/hip_bf16.h>
#include <stdint.h>

// Problem constants (SparseMoE: B=4, T=4096, C=1024, E=8, H=4C, topk=2)
#define NC 1024
#define NE 8
#define NH 4096
#define NN 16384   // B*T tokens

typedef __bf16 bf16x8_t __attribute__((ext_vector_type(8)));
typedef float f32x4_t __attribute__((ext_vector_type(4)));

// Convert 8 fp32 -> 8 bf16, write 16B to LDS/global.
__device__ __forceinline__ void cvt8(const float4 a, const float4 b, __bf16* dst) {
  bf16x8_t r;
  r[0] = (__bf16)a.x; r[1] = (__bf16)a.y; r[2] = (__bf16)a.z; r[3] = (__bf16)a.w;
  r[4] = (__bf16)b.x; r[5] = (__bf16)b.y; r[6] = (__bf16)b.z; r[7] = (__bf16)b.w;
  *(bf16x8_t*)dst = r;
}

// One 128x128x32 MFMA step from swizzled LDS tiles.
__device__ __forceinline__ void mfma_step(const __bf16* __restrict__ Asc,
    const __bf16* __restrict__ Bsc, int a_off, int b_off, f32x4_t (&acc)[4][4]) {
  bf16x8_t af[4], bfr[4];
#pragma unroll
  for (int mi = 0; mi < 4; ++mi) af[mi] = *(const bf16x8_t*)(Asc + a_off + mi * 512);
#pragma unroll
  for (int ni = 0; ni < 4; ++ni) bfr[ni] = *(const bf16x8_t*)(Bsc + b_off + ni * 512);
#pragma unroll
  for (int mi = 0; mi < 4; ++mi)
#pragma unroll
    for (int ni = 0; ni < 4; ++ni)
      acc[mi][ni] = __builtin_amdgcn_mfma_f32_16x16x32_bf16(af[mi], bfr[ni], acc[mi][ni], 0, 0, 0);
}

// Decode fused work: bijective XCD swizzle (m204) + padded-cumsum expert lookup.
// Returns false if this block has no work. GX = grid x-tiles (power of 2).
template<int GX>
__device__ __forceinline__ bool decode_work(const int* __restrict__ counts,
    int& e, int& lr0, int& cnt, int& hbase, int& n0) {
  const int nwg = GX * (int)gridDim.y;
  const int lin = (int)blockIdx.y * GX + (int)blockIdx.x;
  const int q = nwg >> 3, r = nwg & 7;
  const int xcd = lin & 7, idx = lin >> 3;
  const int work = (xcd < r) ? (xcd * (q + 1) + idx)
                             : (r * (q + 1) + (xcd - r) * q + idx);
  const int wx = work & (GX - 1);
  const int wy = work / GX;
  n0 = wx * 128;
  e = -1; lr0 = 0; cnt = 0; hbase = 0;
  int pc = 0, hc = 0;
#pragma unroll
  for (int i = 0; i < NE; ++i) {
    int ci = counts[i]; ci = ci < 0 ? 0 : (ci > NN ? NN : ci);
    const int pb = (ci + 127) >> 7;
    if (e < 0 && wy < pc + pb) { e = i; lr0 = (wy - pc) * 128; cnt = ci; hbase = hc; }
    pc += pb; hc += ci;
  }
  return (e >= 0) && (lr0 < cnt);
}

// ---------------- routing phase A (fp32 exact, double accum): noisy top-2 + probs per token.
__global__ __launch_bounds__(256) void routing_kernel(
    const float* __restrict__ x, const float* __restrict__ eps,
    const float* __restrict__ rw, const float* __restrict__ rb,
    const float* __restrict__ nw, const float* __restrict__ nb,
    int* __restrict__ eidx, float2* __restrict__ pp2) {
  const int lane = threadIdx.x & 63;
  const int n = blockIdx.x * 4 + (threadIdx.x >> 6);  // one wave per token
  if (n >= NN) return;
  double acc[16];
#pragma unroll
  for (int i = 0; i < 16; ++i) acc[i] = 0.0;
  const float* xr = x + (size_t)n * NC;
  for (int c0 = 0; c0 < NC; c0 += 64) {
    const int c = c0 + lane;
    const float xv = xr[c];
    const float4 r0 = *(const float4*)(rw + (size_t)c * NE);
    const float4 r1 = *(const float4*)(rw + (size_t)c * NE + 4);
    const float4 n0 = *(const float4*)(nw + (size_t)c * NE);
    const float4 n1 = *(const float4*)(nw + (size_t)c * NE + 4);
    acc[0] += (double)xv * r0.x;  acc[1] += (double)xv * r0.y;
    acc[2] += (double)xv * r0.z;  acc[3] += (double)xv * r0.w;
    acc[4] += (double)xv * r1.x;  acc[5] += (double)xv * r1.y;
    acc[6] += (double)xv * r1.z;  acc[7] += (double)xv * r1.w;
    acc[8] += (double)xv * n0.x;  acc[9] += (double)xv * n0.y;
    acc[10] += (double)xv * n0.z; acc[11] += (double)xv * n0.w;
    acc[12] += (double)xv * n1.x; acc[13] += (double)xv * n1.y;
    acc[14] += (double)xv * n1.z; acc[15] += (double)xv * n1.w;
  }
#pragma unroll
  for (int off = 32; off > 0; off >>= 1) {
#pragma unroll
    for (int i = 0; i < 16; ++i) acc[i] += __shfl_xor(acc[i], off, 64);
  }
  if (lane == 0) {
    double noisy[NE];
#pragma unroll
    for (int e = 0; e < NE; ++e) {
      const double lg = acc[e] + (double)rb[e];
      const double z = acc[8 + e] + (double)nb[e];
      const double sp = log1p(exp(-fabs(z))) + fmax(z, 0.0);  // stable softplus
      noisy[e] = lg + (double)eps[(size_t)n * NE + e] * sp;
    }
    int i1 = -1, i2 = -1;
    double v1 = -1e300, v2 = -1e300;
#pragma unroll
    for (int e = 0; e < NE; ++e) {  // strict > keeps earlier index on ties (lax.top_k)
      const double v = noisy[e];
      if (v > v1) { v2 = v1; i2 = i1; v1 = v; i1 = e; }
      else if (v > v2) { v2 = v; i2 = e; }
    }
    if (i1 < 0) i1 = 0;                       // hardening vs pathological inputs
    if (i2 < 0 || i2 == i1) i2 = (i1 + 1) & 7;
    const double d = exp(v2 - v1);
    const float p1 = (float)(1.0 / (1.0 + d));
    const float p2 = (float)(d / (1.0 + d));
    eidx[n] = i1 | (i2 << 8);
    pp2[n] = float2{p1, p2};
  }
}

// ---------------- routing phase B: per-expert token lists, block-aggregated atomics.
__global__ __launch_bounds__(256) void build_lists(
    const int* __restrict__ eidx, const float2* __restrict__ pp2,
    int* __restrict__ counts, int* __restrict__ perm, float* __restrict__ pprob) {
  __shared__ int hist[NE];
  __shared__ int base[NE];
  const int t = threadIdx.x;
  if (t < NE) hist[t] = 0;
  __syncthreads();
  const int n = blockIdx.x * 256 + t;
  const int packed = eidx[n];
  const int e1 = packed & 255;
  const int e2 = (packed >> 8) & 255;
  const float2 p = pp2[n];
  const int l1 = atomicAdd(&hist[e1], 1);   // LDS atomic: within-block rank
  const int l2 = atomicAdd(&hist[e2], 1);
  __syncthreads();
  if (t < NE) base[t] = atomicAdd(&counts[t], hist[t]);
  __syncthreads();
  const int o1 = base[e1] + l1;
  const int o2 = base[e2] + l2;
  perm[e1 * NN + o1] = n; pprob[e1 * NN + o1] = p.x;
  perm[e2 * NN + o2] = n; pprob[e2 * NN + o2] = p.y;
}

// ---------------- transpose + fp32->bf16: src fp32 [R][Cc] -> dst bf16 [Cc][R] ----------------
// blockIdx.z selects the expert (matrix stride R*Cc); launch z=1 for single-expert mode.
__global__ __launch_bounds__(256) void transpose_cvt(
    const float* __restrict__ src, __bf16* __restrict__ dst, int R, int Cc) {
  const size_t mat = (size_t)R * Cc;
  src += (size_t)blockIdx.z * mat;
  dst += (size_t)blockIdx.z * mat;
  __shared__ __align__(16) __bf16 tile[64][72];  // +8 pad
  const int r0 = blockIdx.y * 64, c0 = blockIdx.x * 64;
  const int t = threadIdx.x;
  const int tr = t >> 3;            // 0..31
  const int tc = (t & 7) * 8;       // 0..56
#pragma unroll
  for (int h = 0; h < 2; ++h) {
    const int r = tr + h * 32;
    const float* sp = src + (size_t)(r0 + r) * Cc + (c0 + tc);
    const float4 a = *(const float4*)sp;
    const float4 b = *(const float4*)(sp + 4);
    cvt8(a, b, &tile[r][tc]);
  }
  __syncthreads();
#pragma unroll
  for (int h = 0; h < 2; ++h) {
    const int c = tr + h * 32;
    __bf16 tmp[8] __attribute__((aligned(16)));
#pragma unroll
    for (int j = 0; j < 8; ++j) tmp[j] = tile[tc + j][c];
    __bf16* dp = dst + (size_t)(c0 + c) * R + (r0 + tc);
    *(uint4*)dp = *(const uint4*)tmp;
  }
}

// LDS tile geometry (all MFMA GEMMs):
//   As/Bs: 128 rows x 32 k bf16 (64 B rows), T2 XOR-swizzle chunk' = chunk ^ ((r>>1)&3)
//   -> ds_read_b128 conflict-free (verified: SQ_LDS_BANK_CONFLICT 4.46M -> 0 in R4).
//   Depth-2 register prefetch + unroll-by-2 K-loop; one barrier per 32-K.

// ---------------- FUSED GEMM1: all experts, one launch. grid (32, 264). ----------------
// h[hbase+lr] = relu(x[perm_e[lr]] @ w1t[e] + b1[e]); packed hbuf rows by cumsum(counts).
template<int GX>
__global__ __launch_bounds__(256) void moe_gemm1f(
    const float* __restrict__ x, const __bf16* __restrict__ w1t_all,
    const float* __restrict__ b1_all, __bf16* __restrict__ hbuf,
    const int* __restrict__ counts, const int* __restrict__ perm) {
  int e, lr0, cnt, hbase, n0;
  if (!decode_work<GX>(counts, e, lr0, cnt, hbase, n0)) return;
  const int t = threadIdx.x;
  const int* perm_e = perm + e * NN;
  const __bf16* bt = w1t_all + (size_t)e * NC * NH;
  const float* bias = b1_all + (size_t)e * NH;

  __shared__ __align__(16) __bf16 As[2 * 128 * 32];
  __shared__ __align__(16) __bf16 Bs[2 * 128 * 32];

  const int ar1 = lr0 + (t >> 2), ar2 = ar1 + 64;
  const int tokA = (ar1 < cnt) ? perm_e[ar1] : 0;
  const int tokB = (ar2 < cnt) ? perm_e[ar2] : 0;
  const int kg = (t & 3) * 8;
  const float* pA1 = x + (size_t)tokA * NC + kg;
  const float* pA2 = x + (size_t)tokB * NC + kg;
  const int nrow = n0 + (t >> 2);
  const __bf16* pB1 = bt + (size_t)nrow * NC + kg;
  const __bf16* pB2 = bt + (size_t)(nrow + 64) * NC + kg;

  f32x4_t acc[4][4];
#pragma unroll
  for (int i = 0; i < 4; ++i)
#pragma unroll
    for (int j = 0; j < 4; ++j)
#pragma unroll
      for (int k = 0; k < 4; ++k) acc[i][j][k] = 0.f;

  const int lane = t & 63, wid = t >> 6;
  const int wm = (wid >> 1) * 64, wn = (wid & 1) * 64;
  const int col16 = lane & 15, quad = lane >> 4;
  const int woff = (t >> 2) * 32 + (((t & 3) ^ ((t >> 3) & 3)) * 8);
  const int sel = (col16 >> 1) & 3;
  const int a_off = (wm + col16) * 32 + ((quad ^ sel) * 8);
  const int b_off = (wn + col16) * 32 + ((quad ^ sel) * 8);
  __bf16* As0 = As; __bf16* As1 = As + 4096;
  __bf16* Bs0 = Bs; __bf16* Bs1 = Bs + 4096;

  float4 a1a0 = *(const float4*)(pA1),      a1b0 = *(const float4*)(pA1 + 4);
  float4 a2a0 = *(const float4*)(pA2),      a2b0 = *(const float4*)(pA2 + 4);
  uint4  vb10 = *(const uint4*)(pB1),       vb20 = *(const uint4*)(pB2);
  float4 a1a1 = *(const float4*)(pA1 + 32), a1b1 = *(const float4*)(pA1 + 36);
  float4 a2a1 = *(const float4*)(pA2 + 32), a2b1 = *(const float4*)(pA2 + 36);
  uint4  vb11 = *(const uint4*)(pB1 + 32),  vb21 = *(const uint4*)(pB2 + 32);

  for (int k0 = 0; k0 < NC; k0 += 64) {
    cvt8(a1a0, a1b0, As0 + woff);
    cvt8(a2a0, a2b0, As0 + 2048 + woff);
    *(uint4*)(Bs0 + woff) = vb10;
    *(uint4*)(Bs0 + 2048 + woff) = vb20;
    {
      const int kn = (k0 + 64 < NC) ? k0 + 64 : 0;  // clamp: dummy-load, unused
      a1a0 = *(const float4*)(pA1 + kn); a1b0 = *(const float4*)(pA1 + kn + 4);
      a2a0 = *(const float4*)(pA2 + kn); a2b0 = *(const float4*)(pA2 + kn + 4);
      vb10 = *(const uint4*)(pB1 + kn);  vb20 = *(const uint4*)(pB2 + kn);
    }
    __syncthreads();
    mfma_step(As0, Bs0, a_off, b_off, acc);
    cvt8(a1a1, a1b1, As1 + woff);
    cvt8(a2a1, a2b1, As1 + 2048 + woff);
    *(uint4*)(Bs1 + woff) = vb11;
    *(uint4*)(Bs1 + 2048 + woff) = vb21;
    {
      const int kn = (k0 + 96 < NC) ? k0 + 96 : 0;
      a1a1 = *(const float4*)(pA1 + kn); a1b1 = *(const float4*)(pA1 + kn + 4);
      a2a1 = *(const float4*)(pA2 + kn); a2b1 = *(const float4*)(pA2 + kn + 4);
      vb11 = *(const uint4*)(pB1 + kn);  vb21 = *(const uint4*)(pB2 + kn);
    }
    __syncthreads();
    mfma_step(As1, Bs1, a_off, b_off, acc);
  }

  const int colbase = n0 + wn + col16;
#pragma unroll
  for (int mi = 0; mi < 4; ++mi)
#pragma unroll
    for (int reg = 0; reg < 4; ++reg) {
      const int lr = lr0 + wm + mi * 16 + quad * 4 + reg;
      if (lr < cnt) {
        __bf16* hp = hbuf + (size_t)(hbase + lr) * NH + colbase;
#pragma unroll
        for (int ni = 0; ni < 4; ++ni) {
          const float v = acc[mi][ni][reg] + bias[colbase + ni * 16];
          hp[ni * 16] = (__bf16)fmaxf(v, 0.f);
        }
      }
    }
}

// ---------------- FUSED GEMM2: all experts, one launch. grid (8, 264). ----------------
// out[tok] += p * (h @ w2t[e] + b2[e]) via atomicAdd (2 experts/token race-free).
template<int GX>
__global__ __launch_bounds__(256) void moe_gemm2f(
    const __bf16* __restrict__ hbuf, const __bf16* __restrict__ w2t_all,
    const float* __restrict__ b2_all, float* __restrict__ out,
    const int* __restrict__ counts, const int* __restrict__ perm,
    const float* __restrict__ pprob) {
  int e, lr0, cnt, hbase, n0;
  if (!decode_work<GX>(counts, e, lr0, cnt, hbase, n0)) return;
  const int t = threadIdx.x;
  const int* perm_e = perm + e * NN;
  const float* pprob_e = pprob + e * NN;
  const __bf16* bt = w2t_all + (size_t)e * NH * NC;
  const float* bias = b2_all + (size_t)e * NC;

  __shared__ __align__(16) __bf16 As[2 * 128 * 32];
  __shared__ __align__(16) __bf16 Bs[2 * 128 * 32];

  const int lar1 = lr0 + (t >> 2);
  const int kg = (t & 3) * 8;
  const __bf16* pA1 = hbuf + (size_t)(hbase + lar1) * NH + kg;
  const __bf16* pA2 = pA1 + (size_t)64 * NH;
  const int nrow = n0 + (t >> 2);
  const __bf16* pB1 = bt + (size_t)nrow * NH + kg;
  const __bf16* pB2 = bt + (size_t)(nrow + 64) * NH + kg;

  f32x4_t acc[4][4];
#pragma unroll
  for (int i = 0; i < 4; ++i)
#pragma unroll
    for (int j = 0; j < 4; ++j)
#pragma unroll
      for (int k = 0; k < 4; ++k) acc[i][j][k] = 0.f;

  const int lane = t & 63, wid = t >> 6;
  const int wm = (wid >> 1) * 64, wn = (wid & 1) * 64;
  const int col16 = lane & 15, quad = lane >> 4;
  const int woff = (t >> 2) * 32 + (((t & 3) ^ ((t >> 3) & 3)) * 8);
  const int sel = (col16 >> 1) & 3;
  const int a_off = (wm + col16) * 32 + ((quad ^ sel) * 8);
  const int b_off = (wn + col16) * 32 + ((quad ^ sel) * 8);
  __bf16* As0 = As; __bf16* As1 = As + 4096;
  __bf16* Bs0 = Bs; __bf16* Bs1 = Bs + 4096;

  uint4 va10 = *(const uint4*)(pA1),      va20 = *(const uint4*)(pA2);
  uint4 vb10 = *(const uint4*)(pB1),      vb20 = *(const uint4*)(pB2);
  uint4 va11 = *(const uint4*)(pA1 + 32), va21 = *(const uint4*)(pA2 + 32);
  uint4 vb11 = *(const uint4*)(pB1 + 32), vb21 = *(const uint4*)(pB2 + 32);

  for (int k0 = 0; k0 < NH; k0 += 64) {
    *(uint4*)(As0 + woff) = va10;
    *(uint4*)(As0 + 2048 + woff) = va20;
    *(uint4*)(Bs0 + woff) = vb10;
    *(uint4*)(Bs0 + 2048 + woff) = vb20;
    {
      const int kn = (k0 + 64 < NH) ? k0 + 64 : 0;
      va10 = *(const uint4*)(pA1 + kn); va20 = *(const uint4*)(pA2 + kn);
      vb10 = *(const uint4*)(pB1 + kn); vb20 = *(const uint4*)(pB2 + kn);
    }
    __syncthreads();
    mfma_step(As0, Bs0, a_off, b_off, acc);
    *(uint4*)(As1 + woff) = va11;
    *(uint4*)(As1 + 2048 + woff) = va21;
    *(uint4*)(Bs1 + woff) = vb11;
    *(uint4*)(Bs1 + 2048 + woff) = vb21;
    {
      const int kn = (k0 + 96 < NH) ? k0 + 96 : 0;
      va11 = *(const uint4*)(pA1 + kn); va21 = *(const uint4*)(pA2 + kn);
      vb11 = *(const uint4*)(pB1 + kn); vb21 = *(const uint4*)(pB2 + kn);
    }
    __syncthreads();
    mfma_step(As1, Bs1, a_off, b_off, acc);
  }

  const int colbase = n0 + wn + col16;
#pragma unroll
  for (int mi = 0; mi < 4; ++mi)
#pragma unroll
    for (int reg = 0; reg < 4; ++reg) {
      const int lr = lr0 + wm + mi * 16 + quad * 4 + reg;
      if (lr < cnt) {
        const int tok = perm_e[lr];
        const float p = pprob_e[lr];
        float* op = out + (size_t)tok * NC + colbase;
#pragma unroll
        for (int ni = 0; ni < 4; ++ni) {
          atomicAdd(op + ni * 16, (acc[mi][ni][reg] + bias[colbase + ni * 16]) * p);
        }
      }
    }
}

// ---------------- per-expert GEMMs (fallback path, unchanged from R6) ----------------
template<bool FASTB>
__global__ __launch_bounds__(256) void moe_gemm1(
    const float* __restrict__ x, const void* __restrict__ bsrc,
    const float* __restrict__ bias, __bf16* __restrict__ hbuf,
    const int* __restrict__ counts_e, const int* __restrict__ perm_e, int chunk_start) {
  int cnt = *counts_e; if (cnt > NN) cnt = NN; if (cnt < 0) cnt = 0;
  const int lr0 = blockIdx.y * 128;
  const int row0 = chunk_start + lr0;
  if (row0 >= cnt) return;
  const int t = threadIdx.x;

  __shared__ __align__(16) __bf16 As[2 * 128 * 32];
  __shared__ __align__(16) __bf16 Bs[2 * 128 * 32];

  const int ar1 = row0 + (t >> 2), ar2 = ar1 + 64;
  const int tokA = (ar1 < cnt) ? perm_e[ar1] : 0;
  const int tokB = (ar2 < cnt) ? perm_e[ar2] : 0;
  const int kg = (t & 3) * 8;
  const float* pA1 = x + (size_t)tokA * NC + kg;
  const float* pA2 = x + (size_t)tokB * NC + kg;
  const int n0 = blockIdx.x * 128;

  const __bf16* pB1 = nullptr; const __bf16* pB2 = nullptr;
  const float* pBw = nullptr;
  const int kk = t >> 3, cc = (t & 7) * 16;
  if (FASTB) {
    const __bf16* bt = (const __bf16*)bsrc;
    const int nrow = n0 + (t >> 2);
    pB1 = bt + (size_t)nrow * NC + kg;
    pB2 = bt + (size_t)(nrow + 64) * NC + kg;
  } else {
    pBw = (const float*)bsrc + (size_t)kk * NH + n0 + cc;
  }

  f32x4_t acc[4][4];
#pragma unroll
  for (int i = 0; i < 4; ++i)
#pragma unroll
    for (int j = 0; j < 4; ++j)
#pragma unroll
      for (int k = 0; k < 4; ++k) acc[i][j][k] = 0.f;

  const int lane = t & 63, wid = t >> 6;
  const int wm = (wid >> 1) * 64, wn = (wid & 1) * 64;
  const int col16 = lane & 15, quad = lane >> 4;

  if (FASTB) {
    const int woff = (t >> 2) * 32 + (((t & 3) ^ ((t >> 3) & 3)) * 8);
    const int sel = (col16 >> 1) & 3;
    const int a_off = (wm + col16) * 32 + ((quad ^ sel) * 8);
    const int b_off = (wn + col16) * 32 + ((quad ^ sel) * 8);
    __bf16* As0 = As; __bf16* As1 = As + 4096;
    __bf16* Bs0 = Bs; __bf16* Bs1 = Bs + 4096;

    float4 a1a0 = *(const float4*)(pA1),      a1b0 = *(const float4*)(pA1 + 4);
    float4 a2a0 = *(const float4*)(pA2),      a2b0 = *(const float4*)(pA2 + 4);
    uint4  vb10 = *(const uint4*)(pB1),       vb20 = *(const uint4*)(pB2);
    float4 a1a1 = *(const float4*)(pA1 + 32), a1b1 = *(const float4*)(pA1 + 36);
    float4 a2a1 = *(const float4*)(pA2 + 32), a2b1 = *(const float4*)(pA2 + 36);
    uint4  vb11 = *(const uint4*)(pB1 + 32),  vb21 = *(const uint4*)(pB2 + 32);

    for (int k0 = 0; k0 < NC; k0 += 64) {
      cvt8(a1a0, a1b0, As0 + woff);
      cvt8(a2a0, a2b0, As0 + 2048 + woff);
      *(uint4*)(Bs0 + woff) = vb10;
      *(uint4*)(Bs0 + 2048 + woff) = vb20;
      {
        const int kn = (k0 + 64 < NC) ? k0 + 64 : 0;
        a1a0 = *(const float4*)(pA1 + kn); a1b0 = *(const float4*)(pA1 + kn + 4);
        a2a0 = *(const float4*)(pA2 + kn); a2b0 = *(const float4*)(pA2 + kn + 4);
        vb10 = *(const uint4*)(pB1 + kn);  vb20 = *(const uint4*)(pB2 + kn);
      }
      __syncthreads();
      mfma_step(As0, Bs0, a_off, b_off, acc);
      cvt8(a1a1, a1b1, As1 + woff);
      cvt8(a2a1, a2b1, As1 + 2048 + woff);
      *(uint4*)(Bs1 + woff) = vb11;
      *(uint4*)(Bs1 + 2048 + woff) = vb21;
      {
        const int kn = (k0 + 96 < NC) ? k0 + 96 : 0;
        a1a1 = *(const float4*)(pA1 + kn); a1b1 = *(const float4*)(pA1 + kn + 4);
        a2a1 = *(const float4*)(pA2 + kn); a2b1 = *(const float4*)(pA2 + kn + 4);
        vb11 = *(const uint4*)(pB1 + kn);  vb21 = *(const uint4*)(pB2 + kn);
      }
      __syncthreads();
      mfma_step(As1, Bs1, a_off, b_off, acc);
    }
  } else {
    const int a_off = (wm + col16) * 32 + quad * 8;
    for (int k0 = 0; k0 < NC; k0 += 32) {
      const float4 a1a = *(const float4*)(pA1 + k0);
      const float4 a1b = *(const float4*)(pA1 + k0 + 4);
      const float4 a2a = *(const float4*)(pA2 + k0);
      const float4 a2b = *(const float4*)(pA2 + k0 + 4);
      const float* pw = pBw + (size_t)k0 * NH;
      const float4 w0 = *(const float4*)pw;
      const float4 w1 = *(const float4*)(pw + 4);
      const float4 w2 = *(const float4*)(pw + 8);
      const float4 w3 = *(const float4*)(pw + 12);
      __syncthreads();
      cvt8(a1a, a1b, As + t * 8);
      cvt8(a2a, a2b, As + 2048 + t * 8);
      cvt8(w0, w1, Bs + kk * 128 + cc);
      cvt8(w2, w3, Bs + kk * 128 + cc + 8);
      __syncthreads();
      bf16x8_t af[4], bfr[4];
#pragma unroll
      for (int mi = 0; mi < 4; ++mi) af[mi] = *(const bf16x8_t*)(As + a_off + mi * 512);
#pragma unroll
      for (int ni = 0; ni < 4; ++ni) {
        const int bn = wn + ni * 16 + col16;
#pragma unroll
        for (int j = 0; j < 8; ++j) bfr[ni][j] = Bs[(quad * 8 + j) * 128 + bn];
      }
#pragma unroll
      for (int mi = 0; mi < 4; ++mi)
#pragma unroll
        for (int ni = 0; ni < 4; ++ni)
          acc[mi][ni] = __builtin_amdgcn_mfma_f32_16x16x32_bf16(af[mi], bfr[ni], acc[mi][ni], 0, 0, 0);
    }
  }

  const int colbase = n0 + wn + col16;
#pragma unroll
  for (int mi = 0; mi < 4; ++mi)
#pragma unroll
    for (int reg = 0; reg < 4; ++reg) {
      const int lr = lr0 + wm + mi * 16 + quad * 4 + reg;
      if (chunk_start + lr < cnt) {
        __bf16* hp = hbuf + (size_t)lr * NH + colbase;
#pragma unroll
        for (int ni = 0; ni < 4; ++ni) {
          const float v = acc[mi][ni][reg] + bias[colbase + ni * 16];
          hp[ni * 16] = (__bf16)fmaxf(v, 0.f);
        }
      }
    }
}

template<bool FASTB>
__global__ __launch_bounds__(256) void moe_gemm2(
    const __bf16* __restrict__ hbuf, const void* __restrict__ bsrc,
    const float* __restrict__ bias, float* __restrict__ out,
    const int* __restrict__ counts_e, const int* __restrict__ perm_e,
    const float* __restrict__ pprob_e, int chunk_start) {
  int cnt = *counts_e; if (cnt > NN) cnt = NN; if (cnt < 0) cnt = 0;
  const int lr0 = blockIdx.y * 128;
  if (chunk_start + lr0 >= cnt) return;
  const int t = threadIdx.x;

  __shared__ __align__(16) __bf16 As[2 * 128 * 32];
  __shared__ __align__(16) __bf16 Bs[2 * 128 * 32];

  const int lar1 = lr0 + (t >> 2);
  const int kg = (t & 3) * 8;
  const __bf16* pA1 = hbuf + (size_t)lar1 * NH + kg;
  const __bf16* pA2 = pA1 + (size_t)64 * NH;
  const int n0 = blockIdx.x * 128;

  const __bf16* pB1 = nullptr; const __bf16* pB2 = nullptr;
  const float* pBw = nullptr;
  const int kk = t >> 3, cc = (t & 7) * 16;
  if (FASTB) {
    const __bf16* bt = (const __bf16*)bsrc;
    const int nrow = n0 + (t >> 2);
    pB1 = bt + (size_t)nrow * NH + kg;
    pB2 = bt + (size_t)(nrow + 64) * NH + kg;
  } else {
    pBw = (const float*)bsrc + (size_t)kk * NC + n0 + cc;
  }

  f32x4_t acc[4][4];
#pragma unroll
  for (int i = 0; i < 4; ++i)
#pragma unroll
    for (int j = 0; j < 4; ++j)
#pragma unroll
      for (int k = 0; k < 4; ++k) acc[i][j][k] = 0.f;

  const int lane = t & 63, wid = t >> 6;
  const int wm = (wid >> 1) * 64, wn = (wid & 1) * 64;
  const int col16 = lane & 15, quad = lane >> 4;

  if (FASTB) {
    const int woff = (t >> 2) * 32 + (((t & 3) ^ ((t >> 3) & 3)) * 8);
    const int sel = (col16 >> 1) & 3;
    const int a_off = (wm + col16) * 32 + ((quad ^ sel) * 8);
    const int b_off = (wn + col16) * 32 + ((quad ^ sel) * 8);
    __bf16* As0 = As; __bf16* As1 = As + 4096;
    __bf16* Bs0 = Bs; __bf16* Bs1 = Bs + 4096;

    uint4 va10 = *(const uint4*)(pA1),      va20 = *(const uint4*)(pA2);
    uint4 vb10 = *(const uint4*)(pB1),      vb20 = *(const uint4*)(pB2);
    uint4 va11 = *(const uint4*)(pA1 + 32), va21 = *(const uint4*)(pA2 + 32);
    uint4 vb11 = *(const uint4*)(pB1 + 32), vb21 = *(const uint4*)(pB2 + 32);

    for (int k0 = 0; k0 < NH; k0 += 64) {
      *(uint4*)(As0 + woff) = va10;
      *(uint4*)(As0 + 2048 + woff) = va20;
      *(uint4*)(Bs0 + woff) = vb10;
      *(uint4*)(Bs0 + 2048 + woff) = vb20;
      {
        const int kn = (k0 + 64 < NH) ? k0 + 64 : 0;
        va10 = *(const uint4*)(pA1 + kn); va20 = *(const uint4*)(pA2 + kn);
        vb10 = *(const uint4*)(pB1 + kn); vb20 = *(const uint4*)(pB2 + kn);
      }
      __syncthreads();
      mfma_step(As0, Bs0, a_off, b_off, acc);
      *(uint4*)(As1 + woff) = va11;
      *(uint4*)(As1 + 2048 + woff) = va21;
      *(uint4*)(Bs1 + woff) = vb11;
      *(uint4*)(Bs1 + 2048 + woff) = vb21;
      {
        const int kn = (k0 + 96 < NH) ? k0 + 96 : 0;
        va11 = *(const uint4*)(pA1 + kn); va21 = *(const uint4*)(pA2 + kn);
        vb11 = *(const uint4*)(pB1 + kn); vb21 = *(const uint4*)(pB2 + kn);
      }
      __syncthreads();
      mfma_step(As1, Bs1, a_off, b_off, acc);
    }
  } else {
    const int a_off = (wm + col16) * 32 + quad * 8;
    for (int k0 = 0; k0 < NH; k0 += 32) {
      const uint4 va1 = *(const uint4*)(pA1 + k0);
      const uint4 va2 = *(const uint4*)(pA2 + k0);
      const float* pw = pBw + (size_t)k0 * NC;
      const float4 w0 = *(const float4*)pw;
      const float4 w1 = *(const float4*)(pw + 4);
      const float4 w2 = *(const float4*)(pw + 8);
      const float4 w3 = *(const float4*)(pw + 12);
      __syncthreads();
      *(uint4*)(As + t * 8) = va1;
      *(uint4*)(As + 2048 + t * 8) = va2;
      cvt8(w0, w1, Bs + kk * 128 + cc);
      cvt8(w2, w3, Bs + kk * 128 + cc + 8);
      __syncthreads();
      bf16x8_t af[4], bfr[4];
#pragma unroll
      for (int mi = 0; mi < 4; ++mi) af[mi] = *(const bf16x8_t*)(As + a_off + mi * 512);
#pragma unroll
      for (int ni = 0; ni < 4; ++ni) {
        const int bn = wn + ni * 16 + col16;
#pragma unroll
        for (int j = 0; j < 8; ++j) bfr[ni][j] = Bs[(quad * 8 + j) * 128 + bn];
      }
#pragma unroll
      for (int mi = 0; mi < 4; ++mi)
#pragma unroll
        for (int ni = 0; ni < 4; ++ni)
          acc[mi][ni] = __builtin_amdgcn_mfma_f32_16x16x32_bf16(af[mi], bfr[ni], acc[mi][ni], 0, 0, 0);
    }
  }

  const int colbase = n0 + wn + col16;
#pragma unroll
  for (int mi = 0; mi < 4; ++mi)
#pragma unroll
    for (int reg = 0; reg < 4; ++reg) {
      const int lr = lr0 + wm + mi * 16 + quad * 4 + reg;
      const int r = chunk_start + lr;
      if (r < cnt) {
        const int tok = perm_e[r];
        const float p = pprob_e[r];
        float* op = out + (size_t)tok * NC + colbase;
#pragma unroll
        for (int ni = 0; ni < 4; ++ni) {
          op[ni * 16] += (acc[mi][ni][reg] + bias[colbase + ni * 16]) * p;
        }
      }
    }
}

extern "C" void kernel_launch(void* const* d_in, const int* in_sizes, int n_in,
                              void* d_out, int out_size, void* d_ws, size_t ws_size,
                              hipStream_t stream) {
  (void)in_sizes; (void)n_in;
  const float* x   = (const float*)d_in[0];
  const float* eps = (const float*)d_in[1];
  const float* rw  = (const float*)d_in[2];
  const float* rb  = (const float*)d_in[3];
  const float* nw  = (const float*)d_in[4];
  const float* nb  = (const float*)d_in[5];
  const float* w1  = (const float*)d_in[6];
  const float* b1  = (const float*)d_in[7];
  const float* w2  = (const float*)d_in[8];
  const float* b2  = (const float*)d_in[9];
  float* out = (float*)d_out;

  // ws: counts(256B) | perm [E][N] | pprob [E][N] | eidx [N] | pp2 [N] | weights bf16 | hbuf bf16
  char* wsb = (char*)d_ws;
  int* counts = (int*)wsb;
  int* perm = (int*)(wsb + 256);
  float* pprob = (float*)(wsb + 256 + (size_t)NE * NN * 4);
  int* eidx = (int*)(wsb + 256 + (size_t)NE * NN * 8);
  float2* pp2 = (float2*)(wsb + 256 + (size_t)NE * NN * 8 + (size_t)NN * 4);
  size_t off = 256 + (size_t)NE * NN * 8 + (size_t)NN * 12;  // ~1.25 MB

  const size_t wtile = (size_t)NC * NH * 2;             // 8 MB per transposed weight
  const size_t hpack = (size_t)(2 * NN + 256) * NH * 2; // 258 MB packed hbuf (+slack)
  const size_t hfull = (size_t)NN * NH * 2;             // 128 MB per-expert hbuf
  // fusedmode: all-expert weights + packed hbuf -> single-launch GEMMs (TLP fix)
  const bool fusedmode = ws_size >= off + 2 * NE * wtile + hpack + (1u << 20);
  const bool fast2 = fusedmode ||
      ws_size >= off + 2 * NE * wtile + hfull + (4u << 20);
  const bool fast = fast2 ||
      ws_size >= off + 2 * wtile + (size_t)128 * NH * 2 + (1u << 20);
  __bf16* w1t = nullptr; __bf16* w2t = nullptr;
  if (fast2) {
    w1t = (__bf16*)(wsb + off); off += NE * wtile;
    w2t = (__bf16*)(wsb + off); off += NE * wtile;
  } else if (fast) {
    w1t = (__bf16*)(wsb + off); off += wtile;
    w2t = (__bf16*)(wsb + off); off += wtile;
  }
  __bf16* hbuf = (__bf16*)(wsb + off);
  const size_t remain = (ws_size > off) ? (ws_size - off) : 0;
  long rows_cap = (long)(remain / ((size_t)NH * 2));
  rows_cap = (rows_cap / 128) * 128;
  if (rows_cap > NN) rows_cap = NN;
  if (rows_cap < 128) rows_cap = 128;  // floor; needs ws >= ~2.3 MB

  hipMemsetAsync(counts, 0, 256, stream);
  hipMemsetAsync(d_out, 0, (size_t)out_size * 4, stream);

  routing_kernel<<<NN / 4, 256, 0, stream>>>(x, eps, rw, rb, nw, nb, eidx, pp2);
  build_lists<<<NN / 256, 256, 0, stream>>>(eidx, pp2, counts, perm, pprob);

  if (fusedmode) {
    // 6 dispatches total: transpose x2, gemm1f, gemm2f. Grid y=264 covers padded
    // row-blocks (sum ceil(cnt_e/128) <= 263); excess blocks exit on decode.
    transpose_cvt<<<dim3(NH / 64, NC / 64, NE), 256, 0, stream>>>(w1, w1t, NC, NH);
    transpose_cvt<<<dim3(NC / 64, NH / 64, NE), 256, 0, stream>>>(w2, w2t, NH, NC);
    moe_gemm1f<32><<<dim3(32, 264), 256, 0, stream>>>(x, w1t, b1, hbuf, counts, perm);
    moe_gemm2f<8><<<dim3(8, 264), 256, 0, stream>>>(hbuf, w2t, b2, out, counts, perm, pprob);
    return;
  }

  if (fast2) {
    transpose_cvt<<<dim3(NH / 64, NC / 64, NE), 256, 0, stream>>>(w1, w1t, NC, NH);
    transpose_cvt<<<dim3(NC / 64, NH / 64, NE), 256, 0, stream>>>(w2, w2t, NH, NC);
  }

  const int nchunks = (int)((NN + rows_cap - 1) / rows_cap);
  for (int e = 0; e < NE; ++e) {
    const float* w1e = w1 + (size_t)e * NC * NH;
    const float* w2e = w2 + (size_t)e * NH * NC;
    const __bf16* w1te = fast2 ? (w1t + (size_t)e * NC * NH) : w1t;
    const __bf16* w2te = fast2 ? (w2t + (size_t)e * NH * NC) : w2t;
    if (fast && !fast2) {
      transpose_cvt<<<dim3(NH / 64, NC / 64, 1), 256, 0, stream>>>(w1e, w1t, NC, NH);
      transpose_cvt<<<dim3(NC / 64, NH / 64, 1), 256, 0, stream>>>(w2e, w2t, NH, NC);
    }
    for (int ch = 0; ch < nchunks; ++ch) {
      const int cs = ch * (int)rows_cap;
      if (fast) {
        moe_gemm1<true><<<dim3(NH / 128, (unsigned)(rows_cap / 128)), 256, 0, stream>>>(
            x, w1te, b1 + (size_t)e * NH, hbuf, counts + e, perm + (size_t)e * NN, cs);
        moe_gemm2<true><<<dim3(NC / 128, (unsigned)(rows_cap / 128)), 256, 0, stream>>>(
            hbuf, w2te, b2 + (size_t)e * NC, out, counts + e, perm + (size_t)e * NN,
            pprob + (size_t)e * NN, cs);
      } else {
        moe_gemm1<false><<<dim3(NH / 128, (unsigned)(rows_cap / 128)), 256, 0, stream>>>(
            x, w1e, b1 + (size_t)e * NH, hbuf, counts + e, perm + (size_t)e * NN, cs);
        moe_gemm2<false><<<dim3(NC / 128, (unsigned)(rows_cap / 128)), 256, 0, stream>>>(
            hbuf, w2e, b2 + (size_t)e * NC, out, counts + e, perm + (size_t)e * NN,
            pprob + (size_t)e * NN, cs);
      }
    }
  }
}